// Round 11
// baseline (3510.854 us; speedup 1.0000x reference)
//
#include <hip/hip_runtime.h>
#include <stdint.h>

#define NN 100000
#define NE 3200000
#define NNZT (NE + NN)
#define DIM 256
#define WCOLS 2048

typedef __bf16 v8bf __attribute__((ext_vector_type(8)));
typedef float f32x4 __attribute__((ext_vector_type(4)));
typedef float f32x2 __attribute__((ext_vector_type(2)));

__device__ __forceinline__ unsigned f2bfu(float f){
  unsigned u = __builtin_bit_cast(unsigned, f);
  return (u + 0x7FFFu + ((u >> 16) & 1u)) >> 16;
}
__device__ __forceinline__ float lrelu(float x){ return fmaxf(x, 0.2f * x); }
__device__ __forceinline__ int imin(int a, int b){ return a < b ? a : b; }
__device__ __forceinline__ unsigned char f2fp8(float f){
  return (unsigned char)(__builtin_amdgcn_cvt_pk_fp8_f32(f, f, 0, false) & 0xff);
}
// packed dual-FP32 FMA: d = a*b + c on 2-wide f32 (VGPR pairs)
__device__ __forceinline__ f32x2 pkfma(f32x2 a, f32x2 b, f32x2 c){
  f32x2 d;
  asm("v_pk_fma_f32 %0, %1, %2, %3" : "=v"(d) : "v"(a), "v"(b), "v"(c));
  return d;
}
// fp8 dword -> 2 packed bf16 dwords (4 elems) for LDS staging in gemm2
__device__ __forceinline__ void fp8dw_to_bf16x4(int dw, int& o0, int& o1){
  f32x2 lo = __builtin_amdgcn_cvt_pk_f32_fp8(dw, false);
  f32x2 hi = __builtin_amdgcn_cvt_pk_f32_fp8(dw, true);
  o0 = (int)(f2bfu(lo[0]) | (f2bfu(lo[1]) << 16));
  o1 = (int)(f2bfu(hi[0]) | (f2bfu(hi[1]) << 16));
}
// 32 fp8 bytes (two int4) scaled-accumulate into 16 f32x2 accumulators
__device__ __forceinline__ void acc32fp8(int4 u0, int4 u1, f32x2 w2, f32x2* acc2){
  int dws[8] = {u0.x, u0.y, u0.z, u0.w, u1.x, u1.y, u1.z, u1.w};
  #pragma unroll
  for (int m = 0; m < 8; ++m){
    f32x2 lo = __builtin_amdgcn_cvt_pk_f32_fp8(dws[m], false);
    f32x2 hi = __builtin_amdgcn_cvt_pk_f32_fp8(dws[m], true);
    acc2[2*m]   = pkfma(lo, w2, acc2[2*m]);
    acc2[2*m+1] = pkfma(hi, w2, acc2[2*m+1]);
  }
}
// 8 fp8 bytes (uint2) -> v8bf (8 bf16), element order preserved
__device__ __forceinline__ v8bf fp8x8_to_bf16(uint2 raw){
  f32x2 f01 = __builtin_amdgcn_cvt_pk_f32_fp8((int)raw.x, false);
  f32x2 f23 = __builtin_amdgcn_cvt_pk_f32_fp8((int)raw.x, true);
  f32x2 f45 = __builtin_amdgcn_cvt_pk_f32_fp8((int)raw.y, false);
  f32x2 f67 = __builtin_amdgcn_cvt_pk_f32_fp8((int)raw.y, true);
  v8bf r;
  r[0] = (__bf16)f01[0]; r[1] = (__bf16)f01[1];
  r[2] = (__bf16)f23[0]; r[3] = (__bf16)f23[1];
  r[4] = (__bf16)f45[0]; r[5] = (__bf16)f45[1];
  r[6] = (__bf16)f67[0]; r[7] = (__bf16)f67[1];
  return r;
}

// ---- cast x fp32 -> fp8 (4 elems/thread) ----
__global__ void k_cast_x8(const float* __restrict__ x, unsigned char* __restrict__ x8){
  int t = blockIdx.x * 256 + threadIdx.x;           // 6.4M threads exact
  float4 v = ((const float4*)x)[t];
  int lo = __builtin_amdgcn_cvt_pk_fp8_f32(v.x, v.y, 0, false);
  int both = __builtin_amdgcn_cvt_pk_fp8_f32(v.z, v.w, lo, true);
  ((int*)x8)[t] = both;
}

// ---- WaggT[j][h*256+d] = W[d][h*256+j] / 8  (bf16, [256][2048]) ----
// COALESCED READS (W[t] streamed); the scatter is on the store side, which
// doesn't stall the wave (r10 version had 8KB-stride scattered reads).
__global__ void k_make_waggt(const float* __restrict__ W, unsigned short* __restrict__ bt){
  int t = blockIdx.x * 256 + threadIdx.x;           // 524288
  int d = t >> 11, c = t & 2047;                    // W flat index = d*2048 + c
  bt[(size_t)(c & 255) * WCOLS + (c >> 8) * 256 + d] = (unsigned short)f2bfu(W[t] * 0.125f);
}

// ---- Vt[h][k] = sum_d W[k][h*256+d]*a_s[h][d]; Vt[8+h][k] same with a_d (bf16) ----
__global__ void k_make_vt(const float* __restrict__ W, const float* __restrict__ as_,
                          const float* __restrict__ ad_, unsigned short* __restrict__ vt){
  int h = blockIdx.x, k = threadIdx.x;              // 8 x 256
  const float* wr = W + (size_t)k * WCOLS + h * 256;
  const float* a1 = as_ + h * 256;
  const float* a2 = ad_ + h * 256;
  float ss = 0.f, sd = 0.f;
  for (int d = 0; d < 256; ++d){ float wv = wr[d]; ss += wv * a1[d]; sd += wv * a2[d]; }
  vt[h * 256 + k] = (unsigned short)f2bfu(ss);
  vt[(8 + h) * 256 + k] = (unsigned short)f2bfu(sd);
}

// ---- CSR build (structure identical to the round-2/7/10 PASSING kernels) ----
__global__ void k_zero_col(int* __restrict__ col){
  int t = blockIdx.x * 256 + threadIdx.x;
  if (t < NNZT) col[t] = 0;
}
__global__ void k_deg_init(int* __restrict__ deg){
  int t = blockIdx.x * 256 + threadIdx.x;
  if (t < NN) deg[t] = 1;                            // self-loop
}
__global__ void k_hist(const int* __restrict__ ei, int* __restrict__ deg){
  int t = blockIdx.x * 256 + threadIdx.x;            // NE threads exact
  int d = ei[NE + t];
  if ((unsigned)d < NN) atomicAdd(&deg[d], 1);
}
__global__ void __launch_bounds__(1024) k_scan(const int* __restrict__ deg,
                                               int* __restrict__ rp, int* cur){
  __shared__ int ps[1024];
  int t = threadIdx.x;
  int lo = t * 98;
  int hi = lo + 98; if (hi > NN) hi = NN; if (lo > NN) lo = NN;
  int s = 0;
  for (int i = lo; i < hi; ++i) s += deg[i];
  ps[t] = s;
  __syncthreads();
  if (t == 0){
    int run = 0;
    for (int i = 0; i < 1024; ++i){ int v = ps[i]; ps[i] = run; run += v; }
    rp[NN] = run;
  }
  __syncthreads();
  int run = ps[t];
  for (int i = lo; i < hi; ++i){
    int dv = deg[i];
    rp[i] = run; cur[i] = run;
    run += dv;
  }
}
__global__ void k_fill_self(int* __restrict__ cur, int* __restrict__ col){
  int t = blockIdx.x * 256 + threadIdx.x;
  if (t < NN){
    int s = atomicAdd(&cur[t], 1);
    if ((unsigned)s < NNZT) col[s] = t;
  }
}
__global__ void k_fill_edge(const int* __restrict__ ei, int* __restrict__ cur, int* __restrict__ col){
  int t = blockIdx.x * 256 + threadIdx.x;
  int s = ei[t], d = ei[NE + t];
  if ((unsigned)d >= NN) return;                     // matches k_hist guard
  if ((unsigned)s >= NN) s = d;
  int slot = atomicAdd(&cur[d], 1);
  if ((unsigned)slot < NNZT) col[slot] = s;
}

// ---- per-layer P/Q: out = relu?(val*P + Q) ----
__global__ void k_pq(const float* g, const float* be, const float* m, const float* v,
                     const float* __restrict__ b, int has_bn,
                     float* __restrict__ P, float* __restrict__ Q){
  int j = threadIdx.x;
  if (has_bn){
    float A = g[j] * rsqrtf(v[j] + 1e-5f);
    P[j] = A; Q[j] = (b[j] - m[j]) * A + be[j];
  } else {
    P[j] = 1.0f; Q[j] = b[j];
  }
}

// ---- alpha: [als|ald] = x8 @ Vt^T via one MFMA wave per 16 nodes ----
// r7-proven fragment scheme; A-operand converted fp8 -> bf16 in registers.
__global__ void __launch_bounds__(256) k_alpha8(const unsigned char* __restrict__ x8,
    const unsigned short* __restrict__ vt,
    float* __restrict__ als, float* __restrict__ ald){
  int tile = blockIdx.x * 4 + (threadIdx.x >> 6);
  if (tile >= NN / 16) return;                       // 6250 exact
  int lane = threadIdx.x & 63;
  int ri = lane & 15, kg = lane >> 4;
  size_t m0 = (size_t)tile * 16;
  const unsigned char* arow = x8 + (m0 + ri) * DIM;  // row ri of the 16-node tile
  const int4* B = (const int4*)vt;                   // [16][256] bf16
  f32x4 acc = {0.f, 0.f, 0.f, 0.f};
  #pragma unroll
  for (int ks = 0; ks < 8; ++ks){
    uint2 raw = *(const uint2*)(arow + (ks * 4 + kg) * 8);
    v8bf av = fp8x8_to_bf16(raw);
    v8bf bv = __builtin_bit_cast(v8bf, B[ri * 32 + ks * 4 + kg]);
    acc = __builtin_amdgcn_mfma_f32_16x16x32_bf16(av, bv, acc, 0, 0, 0);
  }
  #pragma unroll
  for (int r = 0; r < 4; ++r){
    size_t m = m0 + kg * 4 + r;
    if (ri < 8) als[m * 8 + ri] = acc[r];
    else        ald[m * 8 + (ri - 8)] = acc[r];
  }
}

// ---- aggregation over fp8 x: z8[n, h*256+d] = fp8( (1/den_h) * sum_e w_he * x8[src_e, d] )
// one wave per node; lane = (h = lane&7, dg = lane>>3 owning dims dg*32..+31)
// 4-edge software pipeline: 8 independent x-int4 loads per iteration.
__global__ void __launch_bounds__(256) k_aggregate_x8(const unsigned char* __restrict__ x8,
    const float* __restrict__ als, const float* __restrict__ ald,
    const int* __restrict__ rp, const int* __restrict__ col,
    unsigned char* __restrict__ z8){
  int n = blockIdx.x * 4 + (threadIdx.x >> 6);       // 100000 exact
  int lane = threadIdx.x & 63;
  int h = lane & 7, dg = lane >> 3;
  int start = rp[n], end = rp[n + 1];
  if (start < 0) start = 0;
  if (end > NNZT) end = NNZT;
  if (end < start) end = start;
  float aldv = ald[(size_t)n * 8 + h];
  const unsigned char* xbase = x8 + dg * 32;

  float den = 0.f;
  f32x2 acc2[16];
  #pragma unroll
  for (int i = 0; i < 16; ++i) acc2[i] = (f32x2){0.f, 0.f};

  int e = start;
  int rem = (end - start) & 3;
  for (int i = 0; i < rem; ++i, ++e){
    int src = col[e];
    if ((unsigned)src >= NN) src = n;
    const int4* xp = (const int4*)(xbase + (size_t)src * DIM);
    int4 a0 = xp[0], a1 = xp[1];
    float w = __expf(lrelu(als[(size_t)src * 8 + h] + aldv));
    den += w;
    acc32fp8(a0, a1, (f32x2){w, w}, acc2);
  }
  for (; e < end; e += 4){
    int s0 = col[e], s1 = col[e + 1], s2 = col[e + 2], s3 = col[e + 3];
    if ((unsigned)s0 >= NN) s0 = n;
    if ((unsigned)s1 >= NN) s1 = n;
    if ((unsigned)s2 >= NN) s2 = n;
    if ((unsigned)s3 >= NN) s3 = n;
    const int4* p0 = (const int4*)(xbase + (size_t)s0 * DIM);
    const int4* p1 = (const int4*)(xbase + (size_t)s1 * DIM);
    const int4* p2 = (const int4*)(xbase + (size_t)s2 * DIM);
    const int4* p3 = (const int4*)(xbase + (size_t)s3 * DIM);
    int4 a0 = p0[0], a1 = p0[1];
    int4 b0 = p1[0], b1 = p1[1];
    int4 c0 = p2[0], c1 = p2[1];
    int4 d0 = p3[0], d1 = p3[1];
    float l0 = als[(size_t)s0 * 8 + h];
    float l1 = als[(size_t)s1 * 8 + h];
    float l2 = als[(size_t)s2 * 8 + h];
    float l3 = als[(size_t)s3 * 8 + h];
    float w0 = __expf(lrelu(l0 + aldv));
    float w1 = __expf(lrelu(l1 + aldv));
    float w2 = __expf(lrelu(l2 + aldv));
    float w3 = __expf(lrelu(l3 + aldv));
    den += (w0 + w1) + (w2 + w3);
    acc32fp8(a0, a1, (f32x2){w0, w0}, acc2);
    acc32fp8(b0, b1, (f32x2){w1, w1}, acc2);
    acc32fp8(c0, c1, (f32x2){w2, w2}, acc2);
    acc32fp8(d0, d1, (f32x2){w3, w3}, acc2);
  }

  float r = 1.0f / den;
  unsigned pk[8];
  #pragma unroll
  for (int q = 0; q < 8; ++q){
    float a0 = acc2[2*q][0] * r,   a1 = acc2[2*q][1] * r;
    float a2 = acc2[2*q+1][0] * r, a3 = acc2[2*q+1][1] * r;
    int lo = __builtin_amdgcn_cvt_pk_fp8_f32(a0, a1, 0, false);
    pk[q] = (unsigned)__builtin_amdgcn_cvt_pk_fp8_f32(a2, a3, lo, true);
  }
  unsigned char* zp = z8 + (size_t)n * WCOLS + h * 256 + dg * 32;
  ((uint4*)zp)[0] = make_uint4(pk[0], pk[1], pk[2], pk[3]);
  ((uint4*)zp)[1] = make_uint4(pk[4], pk[5], pk[6], pk[7]);
}

// ---- big GEMM: out[n,j] = sum_k z[n,k] * bt[j,k]; epilogue P/Q (+relu -> fp8 x8) ----
// EXACT r7/r10-proven loop structure.
__global__ void __launch_bounds__(512) k_gemm2(const unsigned char* __restrict__ z8,
    const unsigned short* __restrict__ bt,
    const float* __restrict__ Pb, const float* __restrict__ Qb,
    unsigned char* __restrict__ x8out, float* __restrict__ fout, int last){
  __shared__ __align__(16) unsigned short sA[128 * 64];   // 16 KB
  __shared__ __align__(16) unsigned short sB[256 * 64];   // 32 KB
  int tid = threadIdx.x;
  int w = tid >> 6, lane = tid & 63;
  int wr = w >> 2, wc = w & 3;
  int ri = lane & 15, kg = lane >> 4;
  int m0 = blockIdx.x * 128;

  // A staging: row = tid>>2 (0..127), kq = tid&3 -> 16 fp8 bytes
  int rowA = tid >> 2, kqA = tid & 3;
  int rA = imin(m0 + rowA, NN - 1);
  const unsigned char* zrow = z8 + (size_t)rA * WCOLS + kqA * 16;
  int sAoff0 = rowA * 64 + (((kqA * 2)     ^ (rowA & 7)) * 8);
  int sAoff1 = rowA * 64 + (((kqA * 2 + 1) ^ (rowA & 7)) * 8);

  // B staging: 4 units; row = u>>3 (0..255), lb = u&7 (16B = 8 bf16)
  int rB[4], sBoff[4];
  #pragma unroll
  for (int p = 0; p < 4; ++p){
    int u = tid + p * 512;
    int row = u >> 3, lb = u & 7;
    rB[p] = row;
    sBoff[p] = row * 64 + ((lb ^ (row & 7)) * 8);
  }
  int lbB = tid & 7;

  f32x4 acc[4][4];
  #pragma unroll
  for (int i = 0; i < 4; ++i)
    #pragma unroll
    for (int j = 0; j < 4; ++j) acc[i][j] = (f32x4){0.f, 0.f, 0.f, 0.f};

  for (int t = 0; t < 32; ++t){
    int kbase = t * 64;
    uint4 raw = *(const uint4*)(zrow + kbase);
    int4 vb[4];
    #pragma unroll
    for (int p = 0; p < 4; ++p)
      vb[p] = *(const int4*)(bt + (size_t)rB[p] * WCOLS + kbase + lbB * 8);
    int4 cl, ch;
    fp8dw_to_bf16x4((int)raw.x, cl.x, cl.y);
    fp8dw_to_bf16x4((int)raw.y, cl.z, cl.w);
    fp8dw_to_bf16x4((int)raw.z, ch.x, ch.y);
    fp8dw_to_bf16x4((int)raw.w, ch.z, ch.w);
    *(int4*)(sA + sAoff0) = cl;
    *(int4*)(sA + sAoff1) = ch;
    #pragma unroll
    for (int p = 0; p < 4; ++p) *(int4*)(sB + sBoff[p]) = vb[p];
    __syncthreads();
    #pragma unroll
    for (int ks = 0; ks < 2; ++ks){
      v8bf a[4], b[4];
      #pragma unroll
      for (int ai = 0; ai < 4; ++ai){
        int r = wr * 64 + ai * 16 + ri;
        int pb = (ks * 4 + kg) ^ (r & 7);
        a[ai] = *(const v8bf*)((const unsigned char*)sA + r * 128 + pb * 16);
      }
      #pragma unroll
      for (int bj = 0; bj < 4; ++bj){
        int r = wc * 64 + bj * 16 + ri;
        int pb = (ks * 4 + kg) ^ (r & 7);
        b[bj] = *(const v8bf*)((const unsigned char*)sB + r * 128 + pb * 16);
      }
      #pragma unroll
      for (int ai = 0; ai < 4; ++ai)
        #pragma unroll
        for (int bj = 0; bj < 4; ++bj)
          acc[ai][bj] = __builtin_amdgcn_mfma_f32_16x16x32_bf16(a[ai], b[bj], acc[ai][bj], 0, 0, 0);
    }
    __syncthreads();
  }

  // epilogue: C[m0 + wr*64 + ai*16 + kg*4 + r][wc*64 + bj*16 + ri]
  #pragma unroll
  for (int bj = 0; bj < 4; ++bj){
    int colj = wc * 64 + bj * 16 + ri;
    float p = Pb[colj], q = Qb[colj];
    #pragma unroll
    for (int ai = 0; ai < 4; ++ai){
      #pragma unroll
      for (int r = 0; r < 4; ++r){
        int row = m0 + wr * 64 + ai * 16 + kg * 4 + r;
        if (row < NN){
          float v = acc[ai][bj][r] * p + q;
          if (!last){
            v = fmaxf(v, 0.f);
            x8out[(size_t)row * DIM + colj] = f2fp8(v);
          } else {
            fout[(size_t)row * DIM + colj] = v;
          }
        }
      }
    }
  }
}

// ---- doc GEMM: [64,3072]@[3072,256] fp32, one block per row ----
__global__ void __launch_bounds__(256) k_doc(const float* __restrict__ dd,
    const float* __restrict__ dw, const float* __restrict__ db, float* __restrict__ out){
  int r = blockIdx.x;                 // 64 rows
  int j = threadIdx.x;                // 256 cols
  const float* drow = dd + (size_t)r * 3072;
  float acc = db[j];
  #pragma unroll 4
  for (int k = 0; k < 3072; ++k)
    acc = fmaf(drow[k], dw[(size_t)k * 256 + j], acc);
  out[(size_t)NN * DIM + (size_t)r * 256 + j] = acc;
}

extern "C" void kernel_launch(void* const* d_in, const int* in_sizes, int n_in,
                              void* d_out, int out_size, void* d_ws, size_t ws_size,
                              hipStream_t stream) {
  (void)in_sizes; (void)n_in; (void)out_size; (void)ws_size;
  const float* x      = (const float*)d_in[0];
  const int*   ei     = (const int*)d_in[1];
  const float* doc    = (const float*)d_in[2];
  const float* W[3]   = {(const float*)d_in[3], (const float*)d_in[7], (const float*)d_in[11]};
  const float* as_[3] = {(const float*)d_in[4], (const float*)d_in[8], (const float*)d_in[12]};
  const float* ad_[3] = {(const float*)d_in[5], (const float*)d_in[9], (const float*)d_in[13]};
  const float* b_[3]  = {(const float*)d_in[6], (const float*)d_in[10], (const float*)d_in[14]};
  const float* bng[2] = {(const float*)d_in[15], (const float*)d_in[19]};
  const float* bnb[2] = {(const float*)d_in[16], (const float*)d_in[20]};
  const float* bnm[2] = {(const float*)d_in[17], (const float*)d_in[21]};
  const float* bnv[2] = {(const float*)d_in[18], (const float*)d_in[22]};
  const float* docW   = (const float*)d_in[23];
  const float* docB   = (const float*)d_in[24];
  float* out = (float*)d_out;

  char* ws = (char*)d_ws;
  // Total footprint 254,396,992 B — inside the twice-proven 279,947,840 bound.
  unsigned char*  x8   = (unsigned char*)(ws + 0);             //  25,600,000
  unsigned char*  z8   = (unsigned char*)(ws + 25600000);      // 204,800,000
  float* als           = (float*)(ws + 230400000);             //   3,200,000
  float* ald           = (float*)(ws + 233600000);             //   3,200,000
  unsigned short* bt   = (unsigned short*)(ws + 236800000);    //   3,145,728 (3 x 1 MiB)
  int* rp              = (int*)(ws + 239945728);               //     400,064
  int* deg             = (int*)(ws + 240345792);               //     400,000
  int* cur             = (int*)(ws + 240745792);               //     400,000
  int* colb            = (int*)(ws + 241145792);               //  13,200,000
  unsigned short* vt   = (unsigned short*)(ws + 254345792);    //      24,576 (3 x 8 KiB)
  float* Pb            = (float*)(ws + 254394944);             //       1,024
  float* Qb            = (float*)(ws + 254395968);             //       1,024 -> end 254,396,992

  // input prep
  k_cast_x8<<<25000, 256, 0, stream>>>(x, x8);
  for (int L = 0; L < 3; ++L){
    k_make_waggt<<<2048, 256, 0, stream>>>(W[L], bt + (size_t)L * 524288);
    k_make_vt<<<8, 256, 0, stream>>>(W[L], as_[L], ad_[L], vt + (size_t)L * 4096);
  }

  // CSR (shared by all 3 layers); deg/cur strictly distinct buffers
  k_zero_col<<<12891, 256, 0, stream>>>(colb);
  k_deg_init<<<391, 256, 0, stream>>>(deg);
  k_hist<<<12500, 256, 0, stream>>>(ei, deg);
  k_scan<<<1, 1024, 0, stream>>>(deg, rp, cur);
  k_fill_self<<<391, 256, 0, stream>>>(cur, colb);
  k_fill_edge<<<12500, 256, 0, stream>>>(ei, cur, colb);

  // layers
  for (int L = 0; L < 3; ++L){
    int has_bn = (L < 2) ? 1 : 0;
    k_pq<<<1, 256, 0, stream>>>(has_bn ? bng[L] : nullptr, has_bn ? bnb[L] : nullptr,
                                has_bn ? bnm[L] : nullptr, has_bn ? bnv[L] : nullptr,
                                b_[L], has_bn, Pb, Qb);
    k_alpha8<<<1563, 256, 0, stream>>>(x8, vt + (size_t)L * 4096, als, ald);
    k_aggregate_x8<<<25000, 256, 0, stream>>>(x8, als, ald, rp, colb, z8);
    k_gemm2<<<782, 512, 0, stream>>>(z8, bt + (size_t)L * 524288, Pb, Qb,
                                     x8, out, (L == 2) ? 1 : 0);
  }

  // doc branch
  k_doc<<<64, 256, 0, stream>>>(doc, docW, docB, out);
}

// Round 12
// 2809.698 us; speedup vs baseline: 1.2495x; 1.2495x over previous
//
#include <hip/hip_runtime.h>
#include <stdint.h>

#define NN 100000
#define NE 3200000
#define NNZT (NE + NN)
#define DIM 256
#define WCOLS 2048

typedef __bf16 v8bf __attribute__((ext_vector_type(8)));
typedef float f32x4 __attribute__((ext_vector_type(4)));
typedef float f32x2 __attribute__((ext_vector_type(2)));

__device__ __forceinline__ unsigned f2bfu(float f){
  unsigned u = __builtin_bit_cast(unsigned, f);
  return (u + 0x7FFFu + ((u >> 16) & 1u)) >> 16;
}
__device__ __forceinline__ float lrelu(float x){ return fmaxf(x, 0.2f * x); }
__device__ __forceinline__ int imin(int a, int b){ return a < b ? a : b; }
__device__ __forceinline__ unsigned char f2fp8(float f){
  return (unsigned char)(__builtin_amdgcn_cvt_pk_fp8_f32(f, f, 0, false) & 0xff);
}
// packed dual-FP32 FMA: d = a*b + c on 2-wide f32 (VGPR pairs)
__device__ __forceinline__ f32x2 pkfma(f32x2 a, f32x2 b, f32x2 c){
  f32x2 d;
  asm("v_pk_fma_f32 %0, %1, %2, %3" : "=v"(d) : "v"(a), "v"(b), "v"(c));
  return d;
}
// fp8 dword -> 2 packed bf16 dwords (4 elems) for LDS staging in gemm2
__device__ __forceinline__ void fp8dw_to_bf16x4(int dw, int& o0, int& o1){
  f32x2 lo = __builtin_amdgcn_cvt_pk_f32_fp8(dw, false);
  f32x2 hi = __builtin_amdgcn_cvt_pk_f32_fp8(dw, true);
  o0 = (int)(f2bfu(lo[0]) | (f2bfu(lo[1]) << 16));
  o1 = (int)(f2bfu(hi[0]) | (f2bfu(hi[1]) << 16));
}
// 32 fp8 bytes (two int4) scaled-accumulate into 16 f32x2 accumulators
__device__ __forceinline__ void acc32fp8(int4 u0, int4 u1, f32x2 w2, f32x2* acc2){
  int dws[8] = {u0.x, u0.y, u0.z, u0.w, u1.x, u1.y, u1.z, u1.w};
  #pragma unroll
  for (int m = 0; m < 8; ++m){
    f32x2 lo = __builtin_amdgcn_cvt_pk_f32_fp8(dws[m], false);
    f32x2 hi = __builtin_amdgcn_cvt_pk_f32_fp8(dws[m], true);
    acc2[2*m]   = pkfma(lo, w2, acc2[2*m]);
    acc2[2*m+1] = pkfma(hi, w2, acc2[2*m+1]);
  }
}
// 8 fp8 bytes (uint2) -> v8bf (8 bf16), element order preserved
__device__ __forceinline__ v8bf fp8x8_to_bf16(uint2 raw){
  f32x2 f01 = __builtin_amdgcn_cvt_pk_f32_fp8((int)raw.x, false);
  f32x2 f23 = __builtin_amdgcn_cvt_pk_f32_fp8((int)raw.x, true);
  f32x2 f45 = __builtin_amdgcn_cvt_pk_f32_fp8((int)raw.y, false);
  f32x2 f67 = __builtin_amdgcn_cvt_pk_f32_fp8((int)raw.y, true);
  v8bf r;
  r[0] = (__bf16)f01[0]; r[1] = (__bf16)f01[1];
  r[2] = (__bf16)f23[0]; r[3] = (__bf16)f23[1];
  r[4] = (__bf16)f45[0]; r[5] = (__bf16)f45[1];
  r[6] = (__bf16)f67[0]; r[7] = (__bf16)f67[1];
  return r;
}
// async global -> LDS, 16B per lane; LDS dest is wave-uniform base + lane*16
__device__ __forceinline__ void gl_lds16(const unsigned short* g, unsigned short* l){
  __builtin_amdgcn_global_load_lds(
      (const __attribute__((address_space(1))) void*)g,
      (__attribute__((address_space(3))) void*)l, 16, 0, 0);
}

// ---- cast x fp32 -> fp8 (4 elems/thread) ----
__global__ void k_cast_x8(const float* __restrict__ x, unsigned char* __restrict__ x8){
  int t = blockIdx.x * 256 + threadIdx.x;           // 6.4M threads exact
  float4 v = ((const float4*)x)[t];
  int lo = __builtin_amdgcn_cvt_pk_fp8_f32(v.x, v.y, 0, false);
  int both = __builtin_amdgcn_cvt_pk_fp8_f32(v.z, v.w, lo, true);
  ((int*)x8)[t] = both;
}

// ---- WaggT[j][h*256+d] = W[d][h*256+j] / 8  (bf16, [256][2048]) ----
// coalesced reads; scatter on the store side (r11-proven)
__global__ void k_make_waggt(const float* __restrict__ W, unsigned short* __restrict__ bt){
  int t = blockIdx.x * 256 + threadIdx.x;           // 524288
  int d = t >> 11, c = t & 2047;                    // W flat index = d*2048 + c
  bt[(size_t)(c & 255) * WCOLS + (c >> 8) * 256 + d] = (unsigned short)f2bfu(W[t] * 0.125f);
}

// ---- Vt[h][k] = sum_d W[k][h*256+d]*a_s[h][d]; Vt[8+h][k] same with a_d (bf16) ----
__global__ void k_make_vt(const float* __restrict__ W, const float* __restrict__ as_,
                          const float* __restrict__ ad_, unsigned short* __restrict__ vt){
  int h = blockIdx.x, k = threadIdx.x;              // 8 x 256
  const float* wr = W + (size_t)k * WCOLS + h * 256;
  const float* a1 = as_ + h * 256;
  const float* a2 = ad_ + h * 256;
  float ss = 0.f, sd = 0.f;
  for (int d = 0; d < 256; ++d){ float wv = wr[d]; ss += wv * a1[d]; sd += wv * a2[d]; }
  vt[h * 256 + k] = (unsigned short)f2bfu(ss);
  vt[(8 + h) * 256 + k] = (unsigned short)f2bfu(sd);
}

// ---- CSR build (structure identical to the round-2/7/10 PASSING kernels) ----
__global__ void k_zero_col(int* __restrict__ col){
  int t = blockIdx.x * 256 + threadIdx.x;
  if (t < NNZT) col[t] = 0;
}
__global__ void k_deg_init(int* __restrict__ deg){
  int t = blockIdx.x * 256 + threadIdx.x;
  if (t < NN) deg[t] = 1;                            // self-loop
}
__global__ void k_hist(const int* __restrict__ ei, int* __restrict__ deg){
  int t = blockIdx.x * 256 + threadIdx.x;            // NE threads exact
  int d = ei[NE + t];
  if ((unsigned)d < NN) atomicAdd(&deg[d], 1);
}
__global__ void __launch_bounds__(1024) k_scan(const int* __restrict__ deg,
                                               int* __restrict__ rp, int* cur){
  __shared__ int ps[1024];
  int t = threadIdx.x;
  int lo = t * 98;
  int hi = lo + 98; if (hi > NN) hi = NN; if (lo > NN) lo = NN;
  int s = 0;
  for (int i = lo; i < hi; ++i) s += deg[i];
  ps[t] = s;
  __syncthreads();
  if (t == 0){
    int run = 0;
    for (int i = 0; i < 1024; ++i){ int v = ps[i]; ps[i] = run; run += v; }
    rp[NN] = run;
  }
  __syncthreads();
  int run = ps[t];
  for (int i = lo; i < hi; ++i){
    int dv = deg[i];
    rp[i] = run; cur[i] = run;
    run += dv;
  }
}
__global__ void k_fill_self(int* __restrict__ cur, int* __restrict__ col){
  int t = blockIdx.x * 256 + threadIdx.x;
  if (t < NN){
    int s = atomicAdd(&cur[t], 1);
    if ((unsigned)s < NNZT) col[s] = t;
  }
}
__global__ void k_fill_edge(const int* __restrict__ ei, int* __restrict__ cur, int* __restrict__ col){
  int t = blockIdx.x * 256 + threadIdx.x;
  int s = ei[t], d = ei[NE + t];
  if ((unsigned)d >= NN) return;                     // matches k_hist guard
  if ((unsigned)s >= NN) s = d;
  int slot = atomicAdd(&cur[d], 1);
  if ((unsigned)slot < NNZT) col[slot] = s;
}

// ---- per-layer P/Q: out = relu?(val*P + Q) ----
__global__ void k_pq(const float* g, const float* be, const float* m, const float* v,
                     const float* __restrict__ b, int has_bn,
                     float* __restrict__ P, float* __restrict__ Q){
  int j = threadIdx.x;
  if (has_bn){
    float A = g[j] * rsqrtf(v[j] + 1e-5f);
    P[j] = A; Q[j] = (b[j] - m[j]) * A + be[j];
  } else {
    P[j] = 1.0f; Q[j] = b[j];
  }
}

// ---- alpha: [als|ald] = x8 @ Vt^T via one MFMA wave per 16 nodes (r11-proven) ----
__global__ void __launch_bounds__(256) k_alpha8(const unsigned char* __restrict__ x8,
    const unsigned short* __restrict__ vt,
    float* __restrict__ als, float* __restrict__ ald){
  int tile = blockIdx.x * 4 + (threadIdx.x >> 6);
  if (tile >= NN / 16) return;                       // 6250 exact
  int lane = threadIdx.x & 63;
  int ri = lane & 15, kg = lane >> 4;
  size_t m0 = (size_t)tile * 16;
  const unsigned char* arow = x8 + (m0 + ri) * DIM;  // row ri of the 16-node tile
  const int4* B = (const int4*)vt;                   // [16][256] bf16
  f32x4 acc = {0.f, 0.f, 0.f, 0.f};
  #pragma unroll
  for (int ks = 0; ks < 8; ++ks){
    uint2 raw = *(const uint2*)(arow + (ks * 4 + kg) * 8);
    v8bf av = fp8x8_to_bf16(raw);
    v8bf bv = __builtin_bit_cast(v8bf, B[ri * 32 + ks * 4 + kg]);
    acc = __builtin_amdgcn_mfma_f32_16x16x32_bf16(av, bv, acc, 0, 0, 0);
  }
  #pragma unroll
  for (int r = 0; r < 4; ++r){
    size_t m = m0 + kg * 4 + r;
    if (ri < 8) als[m * 8 + ri] = acc[r];
    else        ald[m * 8 + (ri - 8)] = acc[r];
  }
}

// ---- aggregation (EXACT r10-proven 2-edge pipeline; r11's 4-edge regressed) ----
__global__ void __launch_bounds__(256) k_aggregate_x8(const unsigned char* __restrict__ x8,
    const float* __restrict__ als, const float* __restrict__ ald,
    const int* __restrict__ rp, const int* __restrict__ col,
    unsigned char* __restrict__ z8){
  int n = blockIdx.x * 4 + (threadIdx.x >> 6);       // 100000 exact
  int lane = threadIdx.x & 63;
  int h = lane & 7, dg = lane >> 3;
  int start = rp[n], end = rp[n + 1];
  if (start < 0) start = 0;
  if (end > NNZT) end = NNZT;
  if (end < start) end = start;
  float aldv = ald[(size_t)n * 8 + h];
  const unsigned char* xbase = x8 + dg * 32;

  float den = 0.f;
  f32x2 acc2[16];
  #pragma unroll
  for (int i = 0; i < 16; ++i) acc2[i] = (f32x2){0.f, 0.f};

  int e = start;
  if ((end - start) & 1){                            // peel one edge if odd count
    int src = col[e];
    if ((unsigned)src >= NN) src = n;
    const int4* xp = (const int4*)(xbase + (size_t)src * DIM);
    int4 a0 = xp[0], a1 = xp[1];
    float w = __expf(lrelu(als[(size_t)src * 8 + h] + aldv));
    den += w;
    f32x2 w2 = {w, w};
    acc32fp8(a0, a1, w2, acc2);
    ++e;
  }
  for (; e < end; e += 2){
    int s0 = col[e], s1 = col[e + 1];
    if ((unsigned)s0 >= NN) s0 = n;
    if ((unsigned)s1 >= NN) s1 = n;
    const int4* xp0 = (const int4*)(xbase + (size_t)s0 * DIM);
    const int4* xp1 = (const int4*)(xbase + (size_t)s1 * DIM);
    int4 a0 = xp0[0], a1 = xp0[1];
    int4 b0 = xp1[0], b1 = xp1[1];
    float al0 = als[(size_t)s0 * 8 + h];
    float al1 = als[(size_t)s1 * 8 + h];
    float w0 = __expf(lrelu(al0 + aldv));
    float w1 = __expf(lrelu(al1 + aldv));
    den += w0 + w1;
    f32x2 w20 = {w0, w0}, w21 = {w1, w1};
    acc32fp8(a0, a1, w20, acc2);
    acc32fp8(b0, b1, w21, acc2);
  }

  float r = 1.0f / den;
  unsigned pk[8];
  #pragma unroll
  for (int q = 0; q < 8; ++q){
    float a0 = acc2[2*q][0] * r,   a1 = acc2[2*q][1] * r;
    float a2 = acc2[2*q+1][0] * r, a3 = acc2[2*q+1][1] * r;
    int lo = __builtin_amdgcn_cvt_pk_fp8_f32(a0, a1, 0, false);
    pk[q] = (unsigned)__builtin_amdgcn_cvt_pk_fp8_f32(a2, a3, lo, true);
  }
  unsigned char* zp = z8 + (size_t)n * WCOLS + h * 256 + dg * 32;
  ((uint4*)zp)[0] = make_uint4(pk[0], pk[1], pk[2], pk[3]);
  ((uint4*)zp)[1] = make_uint4(pk[4], pk[5], pk[6], pk[7]);
}

// ---- big GEMM: out[n,j] = sum_k z[n,k] * bt[j,k]; epilogue P/Q (+relu -> fp8 x8) ----
// r7/r10 loop structure, but B staged via global_load_lds (async DMA) with the
// XOR swizzle carried on the per-lane GLOBAL source address (LDS dest linear).
// A (fp8 -> bf16 conversion) stays reg-staged with swizzled ds_write.
__global__ void __launch_bounds__(512) k_gemm2(const unsigned char* __restrict__ z8,
    const unsigned short* __restrict__ bt,
    const float* __restrict__ Pb, const float* __restrict__ Qb,
    unsigned char* __restrict__ x8out, float* __restrict__ fout, int last){
  __shared__ __align__(16) unsigned short sA[128 * 64];   // 16 KB
  __shared__ __align__(16) unsigned short sB[256 * 64];   // 32 KB
  int tid = threadIdx.x;
  int w = tid >> 6, lane = tid & 63;
  int wr = w >> 2, wc = w & 3;
  int ri = lane & 15, kg = lane >> 4;
  int m0 = blockIdx.x * 128;

  // A staging: row = tid>>2 (0..127), kq = tid&3 -> 16 fp8 bytes
  int rowA = tid >> 2, kqA = tid & 3;
  int rA = imin(m0 + rowA, NN - 1);
  const unsigned char* zrow = z8 + (size_t)rA * WCOLS + kqA * 16;
  int sAoff0 = rowA * 64 + (((kqA * 2)     ^ (rowA & 7)) * 8);
  int sAoff1 = rowA * 64 + (((kqA * 2 + 1) ^ (rowA & 7)) * 8);

  // B staging via gl_lds16: wave w, instr p covers rows w*32+p*8 .. +7.
  // lane l -> row_g = w*32 + p*8 + (l>>3), unit = l&7;
  // global col-block carries the swizzle: (l&7) ^ (row_g&7).
  const unsigned short* gbB[4];
  unsigned short* ldsB[4];
  #pragma unroll
  for (int p = 0; p < 4; ++p){
    int row_g = w * 32 + p * 8 + (lane >> 3);
    int blk = (lane & 7) ^ (row_g & 7);
    gbB[p] = bt + (size_t)row_g * WCOLS + blk * 8;
    ldsB[p] = sB + w * 2048 + p * 512;               // wave-uniform dest base
  }

  f32x4 acc[4][4];
  #pragma unroll
  for (int i = 0; i < 4; ++i)
    #pragma unroll
    for (int j = 0; j < 4; ++j) acc[i][j] = (f32x4){0.f, 0.f, 0.f, 0.f};

  for (int t = 0; t < 32; ++t){
    int kbase = t * 64;
    // async B staging (no VGPR data path)
    #pragma unroll
    for (int p = 0; p < 4; ++p) gl_lds16(gbB[p] + kbase, ldsB[p]);
    // A: load fp8, convert to bf16, swizzled ds_write
    uint4 raw = *(const uint4*)(zrow + kbase);
    int4 cl, ch;
    fp8dw_to_bf16x4((int)raw.x, cl.x, cl.y);
    fp8dw_to_bf16x4((int)raw.y, cl.z, cl.w);
    fp8dw_to_bf16x4((int)raw.z, ch.x, ch.y);
    fp8dw_to_bf16x4((int)raw.w, ch.z, ch.w);
    *(int4*)(sA + sAoff0) = cl;
    *(int4*)(sA + sAoff1) = ch;
    __syncthreads();
    #pragma unroll
    for (int ks = 0; ks < 2; ++ks){
      v8bf a[4], b[4];
      #pragma unroll
      for (int ai = 0; ai < 4; ++ai){
        int r = wr * 64 + ai * 16 + ri;
        int pb = (ks * 4 + kg) ^ (r & 7);
        a[ai] = *(const v8bf*)((const unsigned char*)sA + r * 128 + pb * 16);
      }
      #pragma unroll
      for (int bj = 0; bj < 4; ++bj){
        int r = wc * 64 + bj * 16 + ri;
        int pb = (ks * 4 + kg) ^ (r & 7);
        b[bj] = *(const v8bf*)((const unsigned char*)sB + r * 128 + pb * 16);
      }
      #pragma unroll
      for (int ai = 0; ai < 4; ++ai)
        #pragma unroll
        for (int bj = 0; bj < 4; ++bj)
          acc[ai][bj] = __builtin_amdgcn_mfma_f32_16x16x32_bf16(a[ai], b[bj], acc[ai][bj], 0, 0, 0);
    }
    __syncthreads();
  }

  // epilogue: C[m0 + wr*64 + ai*16 + kg*4 + r][wc*64 + bj*16 + ri]
  #pragma unroll
  for (int bj = 0; bj < 4; ++bj){
    int colj = wc * 64 + bj * 16 + ri;
    float p = Pb[colj], q = Qb[colj];
    #pragma unroll
    for (int ai = 0; ai < 4; ++ai){
      #pragma unroll
      for (int r = 0; r < 4; ++r){
        int row = m0 + wr * 64 + ai * 16 + kg * 4 + r;
        if (row < NN){
          float v = acc[ai][bj][r] * p + q;
          if (!last){
            v = fmaxf(v, 0.f);
            x8out[(size_t)row * DIM + colj] = f2fp8(v);
          } else {
            fout[(size_t)row * DIM + colj] = v;
          }
        }
      }
    }
  }
}

// ---- doc GEMM: [64,3072]@[3072,256] fp32, one block per row ----
__global__ void __launch_bounds__(256) k_doc(const float* __restrict__ dd,
    const float* __restrict__ dw, const float* __restrict__ db, float* __restrict__ out){
  int r = blockIdx.x;                 // 64 rows
  int j = threadIdx.x;                // 256 cols
  const float* drow = dd + (size_t)r * 3072;
  float acc = db[j];
  #pragma unroll 4
  for (int k = 0; k < 3072; ++k)
    acc = fmaf(drow[k], dw[(size_t)k * 256 + j], acc);
  out[(size_t)NN * DIM + (size_t)r * 256 + j] = acc;
}

extern "C" void kernel_launch(void* const* d_in, const int* in_sizes, int n_in,
                              void* d_out, int out_size, void* d_ws, size_t ws_size,
                              hipStream_t stream) {
  (void)in_sizes; (void)n_in; (void)out_size; (void)ws_size;
  const float* x      = (const float*)d_in[0];
  const int*   ei     = (const int*)d_in[1];
  const float* doc    = (const float*)d_in[2];
  const float* W[3]   = {(const float*)d_in[3], (const float*)d_in[7], (const float*)d_in[11]};
  const float* as_[3] = {(const float*)d_in[4], (const float*)d_in[8], (const float*)d_in[12]};
  const float* ad_[3] = {(const float*)d_in[5], (const float*)d_in[9], (const float*)d_in[13]};
  const float* b_[3]  = {(const float*)d_in[6], (const float*)d_in[10], (const float*)d_in[14]};
  const float* bng[2] = {(const float*)d_in[15], (const float*)d_in[19]};
  const float* bnb[2] = {(const float*)d_in[16], (const float*)d_in[20]};
  const float* bnm[2] = {(const float*)d_in[17], (const float*)d_in[21]};
  const float* bnv[2] = {(const float*)d_in[18], (const float*)d_in[22]};
  const float* docW   = (const float*)d_in[23];
  const float* docB   = (const float*)d_in[24];
  float* out = (float*)d_out;

  char* ws = (char*)d_ws;
  // Total footprint 254,396,992 B — inside the thrice-proven 279,947,840 bound.
  unsigned char*  x8   = (unsigned char*)(ws + 0);             //  25,600,000
  unsigned char*  z8   = (unsigned char*)(ws + 25600000);      // 204,800,000
  float* als           = (float*)(ws + 230400000);             //   3,200,000
  float* ald           = (float*)(ws + 233600000);             //   3,200,000
  unsigned short* bt   = (unsigned short*)(ws + 236800000);    //   3,145,728 (3 x 1 MiB)
  int* rp              = (int*)(ws + 239945728);               //     400,064
  int* deg             = (int*)(ws + 240345792);               //     400,000
  int* cur             = (int*)(ws + 240745792);               //     400,000
  int* colb            = (int*)(ws + 241145792);               //  13,200,000
  unsigned short* vt   = (unsigned short*)(ws + 254345792);    //      24,576 (3 x 8 KiB)
  float* Pb            = (float*)(ws + 254394944);             //       1,024
  float* Qb            = (float*)(ws + 254395968);             //       1,024 -> end 254,396,992

  // input prep
  k_cast_x8<<<25000, 256, 0, stream>>>(x, x8);
  for (int L = 0; L < 3; ++L){
    k_make_waggt<<<2048, 256, 0, stream>>>(W[L], bt + (size_t)L * 524288);
    k_make_vt<<<8, 256, 0, stream>>>(W[L], as_[L], ad_[L], vt + (size_t)L * 4096);
  }

  // CSR (shared by all 3 layers); deg/cur strictly distinct buffers
  k_zero_col<<<12891, 256, 0, stream>>>(colb);
  k_deg_init<<<391, 256, 0, stream>>>(deg);
  k_hist<<<12500, 256, 0, stream>>>(ei, deg);
  k_scan<<<1, 1024, 0, stream>>>(deg, rp, cur);
  k_fill_self<<<391, 256, 0, stream>>>(cur, colb);
  k_fill_edge<<<12500, 256, 0, stream>>>(ei, cur, colb);

  // layers
  for (int L = 0; L < 3; ++L){
    int has_bn = (L < 2) ? 1 : 0;
    k_pq<<<1, 256, 0, stream>>>(has_bn ? bng[L] : nullptr, has_bn ? bnb[L] : nullptr,
                                has_bn ? bnm[L] : nullptr, has_bn ? bnv[L] : nullptr,
                                b_[L], has_bn, Pb, Qb);
    k_alpha8<<<1563, 256, 0, stream>>>(x8, vt + (size_t)L * 4096, als, ald);
    k_aggregate_x8<<<25000, 256, 0, stream>>>(x8, als, ald, rp, colb, z8);
    k_gemm2<<<782, 512, 0, stream>>>(z8, bt + (size_t)L * 524288, Pb, Qb,
                                     x8, out, (L == 2) ? 1 : 0);
  }

  // doc branch
  k_doc<<<64, 256, 0, stream>>>(doc, docW, docB, out);
}

// Round 13
// 2788.577 us; speedup vs baseline: 1.2590x; 1.0076x over previous
//
#include <hip/hip_runtime.h>
#include <stdint.h>

#define NN 100000
#define NE 3200000
#define NNZT (NE + NN)
#define DIM 256
#define WCOLS 2048

typedef __bf16 v8bf __attribute__((ext_vector_type(8)));
typedef float f32x4 __attribute__((ext_vector_type(4)));
typedef float f32x2 __attribute__((ext_vector_type(2)));

__device__ __forceinline__ unsigned f2bfu(float f){
  unsigned u = __builtin_bit_cast(unsigned, f);
  return (u + 0x7FFFu + ((u >> 16) & 1u)) >> 16;
}
__device__ __forceinline__ float lrelu(float x){ return fmaxf(x, 0.2f * x); }
__device__ __forceinline__ int imin(int a, int b){ return a < b ? a : b; }
__device__ __forceinline__ unsigned char f2fp8(float f){
  return (unsigned char)(__builtin_amdgcn_cvt_pk_fp8_f32(f, f, 0, false) & 0xff);
}
// packed dual-FP32 FMA: d = a*b + c on 2-wide f32 (VGPR pairs)
__device__ __forceinline__ f32x2 pkfma(f32x2 a, f32x2 b, f32x2 c){
  f32x2 d;
  asm("v_pk_fma_f32 %0, %1, %2, %3" : "=v"(d) : "v"(a), "v"(b), "v"(c));
  return d;
}
// 32 fp8 bytes (two int4) scaled-accumulate into 16 f32x2 accumulators
__device__ __forceinline__ void acc32fp8(int4 u0, int4 u1, f32x2 w2, f32x2* acc2){
  int dws[8] = {u0.x, u0.y, u0.z, u0.w, u1.x, u1.y, u1.z, u1.w};
  #pragma unroll
  for (int m = 0; m < 8; ++m){
    f32x2 lo = __builtin_amdgcn_cvt_pk_f32_fp8(dws[m], false);
    f32x2 hi = __builtin_amdgcn_cvt_pk_f32_fp8(dws[m], true);
    acc2[2*m]   = pkfma(lo, w2, acc2[2*m]);
    acc2[2*m+1] = pkfma(hi, w2, acc2[2*m+1]);
  }
}
// 8 fp8 bytes (uint2) -> v8bf (8 bf16), element order preserved
__device__ __forceinline__ v8bf fp8x8_to_bf16(uint2 raw){
  f32x2 f01 = __builtin_amdgcn_cvt_pk_f32_fp8((int)raw.x, false);
  f32x2 f23 = __builtin_amdgcn_cvt_pk_f32_fp8((int)raw.x, true);
  f32x2 f45 = __builtin_amdgcn_cvt_pk_f32_fp8((int)raw.y, false);
  f32x2 f67 = __builtin_amdgcn_cvt_pk_f32_fp8((int)raw.y, true);
  v8bf r;
  r[0] = (__bf16)f01[0]; r[1] = (__bf16)f01[1];
  r[2] = (__bf16)f23[0]; r[3] = (__bf16)f23[1];
  r[4] = (__bf16)f45[0]; r[5] = (__bf16)f45[1];
  r[6] = (__bf16)f67[0]; r[7] = (__bf16)f67[1];
  return r;
}
// async global -> LDS, 16B per lane; LDS dest is wave-uniform base + lane*16
__device__ __forceinline__ void gl_lds16(const void* g, void* l){
  __builtin_amdgcn_global_load_lds(
      (const __attribute__((address_space(1))) void*)g,
      (__attribute__((address_space(3))) void*)l, 16, 0, 0);
}
__device__ __forceinline__ long long mk64(unsigned lo, unsigned hi){
  return (long long)(((unsigned long long)hi << 32) | lo);
}

// ---- cast x fp32 -> fp8 (4 elems/thread) ----
__global__ void k_cast_x8(const float* __restrict__ x, unsigned char* __restrict__ x8){
  int t = blockIdx.x * 256 + threadIdx.x;           // 6.4M threads exact
  float4 v = ((const float4*)x)[t];
  int lo = __builtin_amdgcn_cvt_pk_fp8_f32(v.x, v.y, 0, false);
  int both = __builtin_amdgcn_cvt_pk_fp8_f32(v.z, v.w, lo, true);
  ((int*)x8)[t] = both;
}

// ---- WaggT8[j][h*256+d] = fp8( W[d][h*256+j] * 8 )  ([256][2048] fp8) ----
// x8 scale: W*8 keeps values in e4m3 normal range; epilogue folds /64.
// coalesced reads; scatter on the store side (r11-proven pattern)
__global__ void k_make_waggt8(const float* __restrict__ W, unsigned char* __restrict__ bt8){
  int t = blockIdx.x * 256 + threadIdx.x;           // 524288
  int d = t >> 11, c = t & 2047;                    // W flat index = d*2048 + c
  bt8[(size_t)(c & 255) * WCOLS + (c >> 8) * 256 + d] = f2fp8(W[t] * 8.0f);
}

// ---- Vt[h][k] = sum_d W[k][h*256+d]*a_s[h][d]; Vt[8+h][k] same with a_d (bf16) ----
__global__ void k_make_vt(const float* __restrict__ W, const float* __restrict__ as_,
                          const float* __restrict__ ad_, unsigned short* __restrict__ vt){
  int h = blockIdx.x, k = threadIdx.x;              // 8 x 256
  const float* wr = W + (size_t)k * WCOLS + h * 256;
  const float* a1 = as_ + h * 256;
  const float* a2 = ad_ + h * 256;
  float ss = 0.f, sd = 0.f;
  for (int d = 0; d < 256; ++d){ float wv = wr[d]; ss += wv * a1[d]; sd += wv * a2[d]; }
  vt[h * 256 + k] = (unsigned short)f2bfu(ss);
  vt[(8 + h) * 256 + k] = (unsigned short)f2bfu(sd);
}

// ---- CSR build (structure identical to the round-2/7/10/12 PASSING kernels) ----
__global__ void k_zero_col(int* __restrict__ col){
  int t = blockIdx.x * 256 + threadIdx.x;
  if (t < NNZT) col[t] = 0;
}
__global__ void k_deg_init(int* __restrict__ deg){
  int t = blockIdx.x * 256 + threadIdx.x;
  if (t < NN) deg[t] = 1;                            // self-loop
}
__global__ void k_hist(const int* __restrict__ ei, int* __restrict__ deg){
  int t = blockIdx.x * 256 + threadIdx.x;            // NE threads exact
  int d = ei[NE + t];
  if ((unsigned)d < NN) atomicAdd(&deg[d], 1);
}
__global__ void __launch_bounds__(1024) k_scan(const int* __restrict__ deg,
                                               int* __restrict__ rp, int* cur){
  __shared__ int ps[1024];
  int t = threadIdx.x;
  int lo = t * 98;
  int hi = lo + 98; if (hi > NN) hi = NN; if (lo > NN) lo = NN;
  int s = 0;
  for (int i = lo; i < hi; ++i) s += deg[i];
  ps[t] = s;
  __syncthreads();
  if (t == 0){
    int run = 0;
    for (int i = 0; i < 1024; ++i){ int v = ps[i]; ps[i] = run; run += v; }
    rp[NN] = run;
  }
  __syncthreads();
  int run = ps[t];
  for (int i = lo; i < hi; ++i){
    int dv = deg[i];
    rp[i] = run; cur[i] = run;
    run += dv;
  }
}
__global__ void k_fill_self(int* __restrict__ cur, int* __restrict__ col){
  int t = blockIdx.x * 256 + threadIdx.x;
  if (t < NN){
    int s = atomicAdd(&cur[t], 1);
    if ((unsigned)s < NNZT) col[s] = t;
  }
}
__global__ void k_fill_edge(const int* __restrict__ ei, int* __restrict__ cur, int* __restrict__ col){
  int t = blockIdx.x * 256 + threadIdx.x;
  int s = ei[t], d = ei[NE + t];
  if ((unsigned)d >= NN) return;                     // matches k_hist guard
  if ((unsigned)s >= NN) s = d;
  int slot = atomicAdd(&cur[d], 1);
  if ((unsigned)slot < NNZT) col[slot] = s;
}

// ---- per-layer P/Q: out = relu?(acc*P + Q); P carries the fp8-GEMM /64 fold ----
__global__ void k_pq(const float* g, const float* be, const float* m, const float* v,
                     const float* __restrict__ b, int has_bn,
                     float* __restrict__ P, float* __restrict__ Q){
  int j = threadIdx.x;
  if (has_bn){
    float A = g[j] * rsqrtf(v[j] + 1e-5f);
    P[j] = A * 0.015625f;                            // A/64
    Q[j] = (b[j] - m[j]) * A + be[j];
  } else {
    P[j] = 0.015625f;                                // 1/64
    Q[j] = b[j];
  }
}

// ---- alpha: [als|ald] = x8 @ Vt^T via one MFMA wave per 16 nodes (r11-proven) ----
__global__ void __launch_bounds__(256) k_alpha8(const unsigned char* __restrict__ x8,
    const unsigned short* __restrict__ vt,
    float* __restrict__ als, float* __restrict__ ald){
  int tile = blockIdx.x * 4 + (threadIdx.x >> 6);
  if (tile >= NN / 16) return;                       // 6250 exact
  int lane = threadIdx.x & 63;
  int ri = lane & 15, kg = lane >> 4;
  size_t m0 = (size_t)tile * 16;
  const unsigned char* arow = x8 + (m0 + ri) * DIM;  // row ri of the 16-node tile
  const int4* B = (const int4*)vt;                   // [16][256] bf16
  f32x4 acc = {0.f, 0.f, 0.f, 0.f};
  #pragma unroll
  for (int ks = 0; ks < 8; ++ks){
    uint2 raw = *(const uint2*)(arow + (ks * 4 + kg) * 8);
    v8bf av = fp8x8_to_bf16(raw);
    v8bf bv = __builtin_bit_cast(v8bf, B[ri * 32 + ks * 4 + kg]);
    acc = __builtin_amdgcn_mfma_f32_16x16x32_bf16(av, bv, acc, 0, 0, 0);
  }
  #pragma unroll
  for (int r = 0; r < 4; ++r){
    size_t m = m0 + kg * 4 + r;
    if (ri < 8) als[m * 8 + ri] = acc[r];
    else        ald[m * 8 + (ri - 8)] = acc[r];
  }
}

// ---- aggregation (EXACT r10/r12-proven 2-edge pipeline) ----
__global__ void __launch_bounds__(256) k_aggregate_x8(const unsigned char* __restrict__ x8,
    const float* __restrict__ als, const float* __restrict__ ald,
    const int* __restrict__ rp, const int* __restrict__ col,
    unsigned char* __restrict__ z8){
  int n = blockIdx.x * 4 + (threadIdx.x >> 6);       // 100000 exact
  int lane = threadIdx.x & 63;
  int h = lane & 7, dg = lane >> 3;
  int start = rp[n], end = rp[n + 1];
  if (start < 0) start = 0;
  if (end > NNZT) end = NNZT;
  if (end < start) end = start;
  float aldv = ald[(size_t)n * 8 + h];
  const unsigned char* xbase = x8 + dg * 32;

  float den = 0.f;
  f32x2 acc2[16];
  #pragma unroll
  for (int i = 0; i < 16; ++i) acc2[i] = (f32x2){0.f, 0.f};

  int e = start;
  if ((end - start) & 1){                            // peel one edge if odd count
    int src = col[e];
    if ((unsigned)src >= NN) src = n;
    const int4* xp = (const int4*)(xbase + (size_t)src * DIM);
    int4 a0 = xp[0], a1 = xp[1];
    float w = __expf(lrelu(als[(size_t)src * 8 + h] + aldv));
    den += w;
    f32x2 w2 = {w, w};
    acc32fp8(a0, a1, w2, acc2);
    ++e;
  }
  for (; e < end; e += 2){
    int s0 = col[e], s1 = col[e + 1];
    if ((unsigned)s0 >= NN) s0 = n;
    if ((unsigned)s1 >= NN) s1 = n;
    const int4* xp0 = (const int4*)(xbase + (size_t)s0 * DIM);
    const int4* xp1 = (const int4*)(xbase + (size_t)s1 * DIM);
    int4 a0 = xp0[0], a1 = xp0[1];
    int4 b0 = xp1[0], b1 = xp1[1];
    float al0 = als[(size_t)s0 * 8 + h];
    float al1 = als[(size_t)s1 * 8 + h];
    float w0 = __expf(lrelu(al0 + aldv));
    float w1 = __expf(lrelu(al1 + aldv));
    den += w0 + w1;
    f32x2 w20 = {w0, w0}, w21 = {w1, w1};
    acc32fp8(a0, a1, w20, acc2);
    acc32fp8(b0, b1, w21, acc2);
  }

  float r = 1.0f / den;
  unsigned pk[8];
  #pragma unroll
  for (int q = 0; q < 8; ++q){
    float a0 = acc2[2*q][0] * r,   a1 = acc2[2*q][1] * r;
    float a2 = acc2[2*q+1][0] * r, a3 = acc2[2*q+1][1] * r;
    int lo = __builtin_amdgcn_cvt_pk_fp8_f32(a0, a1, 0, false);
    pk[q] = (unsigned)__builtin_amdgcn_cvt_pk_fp8_f32(a2, a3, lo, true);
  }
  unsigned char* zp = z8 + (size_t)n * WCOLS + h * 256 + dg * 32;
  ((uint4*)zp)[0] = make_uint4(pk[0], pk[1], pk[2], pk[3]);
  ((uint4*)zp)[1] = make_uint4(pk[4], pk[5], pk[6], pk[7]);
}

// ---- big GEMM, full fp8: out[n,j] = sum_k z8[n,k] * bt8[j,k] via
// mfma_f32_16x16x32_fp8_fp8 (bf16 rate). BOTH operands staged with pure
// global_load_lds (no VALU conversion, no ds_write). 16B-block XOR swizzle
// blk ^ ((row>>1)&3) carried on the GLOBAL source (LDS dest linear).
// Each ds_read_b128 = one 16B block = fragment pair (MFMA k-chunks are a
// permutation of k, applied identically to A and B -> dot product exact).
__global__ void __launch_bounds__(512) k_gemm2(const unsigned char* __restrict__ z8,
    const unsigned char* __restrict__ bt8,
    const float* __restrict__ Pb, const float* __restrict__ Qb,
    unsigned char* __restrict__ x8out, float* __restrict__ fout, int last){
  __shared__ __align__(16) unsigned char sA[128 * 64];   // 8 KB
  __shared__ __align__(16) unsigned char sB[256 * 64];   // 16 KB
  int tid = threadIdx.x;
  int w = tid >> 6, lane = tid & 63;
  int wr = w >> 2, wc = w & 3;
  int ri = lane & 15, kg = lane >> 4;
  int m0 = blockIdx.x * 128;

  // staging source addresses (16B units, swizzled on the global side)
  int rowU = tid >> 2;                         // 0..127
  int gblk = (tid & 3) ^ ((tid >> 3) & 3);     // = (u&3) ^ ((row>>1)&3), both A and B
  int rA = imin(m0 + rowU, NN - 1);
  const unsigned char* gA  = z8  + (size_t)rA * WCOLS + gblk * 16;
  const unsigned char* gB0 = bt8 + (size_t)rowU * WCOLS + gblk * 16;          // rows 0..127
  const unsigned char* gB1 = bt8 + (size_t)(128 + rowU) * WCOLS + gblk * 16;  // rows 128..255
  unsigned char* ldsA  = sA + (w << 10);
  unsigned char* ldsB0 = sB + (w << 10);
  unsigned char* ldsB1 = sB + 8192 + (w << 10);

  f32x4 acc[4][4];
  #pragma unroll
  for (int i = 0; i < 4; ++i)
    #pragma unroll
    for (int j = 0; j < 4; ++j) acc[i][j] = (f32x4){0.f, 0.f, 0.f, 0.f};

  for (int t = 0; t < 32; ++t){
    int kbase = t * 64;
    gl_lds16(gA + kbase, ldsA);
    gl_lds16(gB0 + kbase, ldsB0);
    gl_lds16(gB1 + kbase, ldsB1);
    __syncthreads();                           // drains gl_lds (vmcnt 0)

    long long aLo[4], aHi[4], bLo[4], bHi[4];
    #pragma unroll
    for (int ai = 0; ai < 4; ++ai){
      int r = wr * 64 + ai * 16 + ri;
      int c = kg ^ ((r >> 1) & 3);
      uint4 av = *(const uint4*)(sA + r * 64 + c * 16);
      aLo[ai] = mk64(av.x, av.y);
      aHi[ai] = mk64(av.z, av.w);
    }
    #pragma unroll
    for (int bj = 0; bj < 4; ++bj){
      int r = wc * 64 + bj * 16 + ri;
      int c = kg ^ ((r >> 1) & 3);
      uint4 bv = *(const uint4*)(sB + r * 64 + c * 16);
      bLo[bj] = mk64(bv.x, bv.y);
      bHi[bj] = mk64(bv.z, bv.w);
    }
    #pragma unroll
    for (int ai = 0; ai < 4; ++ai)
      #pragma unroll
      for (int bj = 0; bj < 4; ++bj){
        acc[ai][bj] = __builtin_amdgcn_mfma_f32_16x16x32_fp8_fp8(aLo[ai], bLo[bj], acc[ai][bj], 0, 0, 0);
        acc[ai][bj] = __builtin_amdgcn_mfma_f32_16x16x32_fp8_fp8(aHi[ai], bHi[bj], acc[ai][bj], 0, 0, 0);
      }
    __syncthreads();
  }

  // epilogue: C[m0 + wr*64 + ai*16 + kg*4 + r][wc*64 + bj*16 + ri]
  #pragma unroll
  for (int bj = 0; bj < 4; ++bj){
    int colj = wc * 64 + bj * 16 + ri;
    float p = Pb[colj], q = Qb[colj];
    #pragma unroll
    for (int ai = 0; ai < 4; ++ai){
      #pragma unroll
      for (int r = 0; r < 4; ++r){
        int row = m0 + wr * 64 + ai * 16 + kg * 4 + r;
        if (row < NN){
          float v = acc[ai][bj][r] * p + q;
          if (!last){
            v = fmaxf(v, 0.f);
            x8out[(size_t)row * DIM + colj] = f2fp8(v);
          } else {
            fout[(size_t)row * DIM + colj] = v;
          }
        }
      }
    }
  }
}

// ---- doc GEMM: [64,3072]@[3072,256] fp32, one block per row ----
__global__ void __launch_bounds__(256) k_doc(const float* __restrict__ dd,
    const float* __restrict__ dw, const float* __restrict__ db, float* __restrict__ out){
  int r = blockIdx.x;                 // 64 rows
  int j = threadIdx.x;                // 256 cols
  const float* drow = dd + (size_t)r * 3072;
  float acc = db[j];
  #pragma unroll 4
  for (int k = 0; k < 3072; ++k)
    acc = fmaf(drow[k], dw[(size_t)k * 256 + j], acc);
  out[(size_t)NN * DIM + (size_t)r * 256 + j] = acc;
}

extern "C" void kernel_launch(void* const* d_in, const int* in_sizes, int n_in,
                              void* d_out, int out_size, void* d_ws, size_t ws_size,
                              hipStream_t stream) {
  (void)in_sizes; (void)n_in; (void)out_size; (void)ws_size;
  const float* x      = (const float*)d_in[0];
  const int*   ei     = (const int*)d_in[1];
  const float* doc    = (const float*)d_in[2];
  const float* W[3]   = {(const float*)d_in[3], (const float*)d_in[7], (const float*)d_in[11]};
  const float* as_[3] = {(const float*)d_in[4], (const float*)d_in[8], (const float*)d_in[12]};
  const float* ad_[3] = {(const float*)d_in[5], (const float*)d_in[9], (const float*)d_in[13]};
  const float* b_[3]  = {(const float*)d_in[6], (const float*)d_in[10], (const float*)d_in[14]};
  const float* bng[2] = {(const float*)d_in[15], (const float*)d_in[19]};
  const float* bnb[2] = {(const float*)d_in[16], (const float*)d_in[20]};
  const float* bnm[2] = {(const float*)d_in[17], (const float*)d_in[21]};
  const float* bnv[2] = {(const float*)d_in[18], (const float*)d_in[22]};
  const float* docW   = (const float*)d_in[23];
  const float* docB   = (const float*)d_in[24];
  float* out = (float*)d_out;

  char* ws = (char*)d_ws;
  // Same offsets as the r10/r12 PASSING layout (bt region now holds fp8, half-used).
  unsigned char*  x8   = (unsigned char*)(ws + 0);             //  25,600,000
  unsigned char*  z8   = (unsigned char*)(ws + 25600000);      // 204,800,000
  float* als           = (float*)(ws + 230400000);             //   3,200,000
  float* ald           = (float*)(ws + 233600000);             //   3,200,000
  unsigned char* bt8   = (unsigned char*)(ws + 236800000);     //   1,572,864 used (3 x 512 KiB)
  int* rp              = (int*)(ws + 239945728);               //     400,064
  int* deg             = (int*)(ws + 240345792);               //     400,000
  int* cur             = (int*)(ws + 240745792);               //     400,000
  int* colb            = (int*)(ws + 241145792);               //  13,200,000
  unsigned short* vt   = (unsigned short*)(ws + 254345792);    //      24,576 (3 x 8 KiB)
  float* Pb            = (float*)(ws + 254394944);             //       1,024
  float* Qb            = (float*)(ws + 254395968);             //       1,024 -> end 254,396,992

  // input prep
  k_cast_x8<<<25000, 256, 0, stream>>>(x, x8);
  for (int L = 0; L < 3; ++L){
    k_make_waggt8<<<2048, 256, 0, stream>>>(W[L], bt8 + (size_t)L * 524288);
    k_make_vt<<<8, 256, 0, stream>>>(W[L], as_[L], ad_[L], vt + (size_t)L * 4096);
  }

  // CSR (shared by all 3 layers); deg/cur strictly distinct buffers
  k_zero_col<<<12891, 256, 0, stream>>>(colb);
  k_deg_init<<<391, 256, 0, stream>>>(deg);
  k_hist<<<12500, 256, 0, stream>>>(ei, deg);
  k_scan<<<1, 1024, 0, stream>>>(deg, rp, cur);
  k_fill_self<<<391, 256, 0, stream>>>(cur, colb);
  k_fill_edge<<<12500, 256, 0, stream>>>(ei, cur, colb);

  // layers
  for (int L = 0; L < 3; ++L){
    int has_bn = (L < 2) ? 1 : 0;
    k_pq<<<1, 256, 0, stream>>>(has_bn ? bng[L] : nullptr, has_bn ? bnb[L] : nullptr,
                                has_bn ? bnm[L] : nullptr, has_bn ? bnv[L] : nullptr,
                                b_[L], has_bn, Pb, Qb);
    k_alpha8<<<1563, 256, 0, stream>>>(x8, vt + (size_t)L * 4096, als, ald);
    k_aggregate_x8<<<25000, 256, 0, stream>>>(x8, als, ald, rp, colb, z8);
    k_gemm2<<<782, 512, 0, stream>>>(z8, bt8 + (size_t)L * 524288, Pb, Qb,
                                     x8, out, (L == 2) ? 1 : 0);
  }

  // doc branch
  k_doc<<<64, 256, 0, stream>>>(doc, docW, docB, out);
}

// Round 14
// 2200.643 us; speedup vs baseline: 1.5954x; 1.2672x over previous
//
#include <hip/hip_runtime.h>
#include <stdint.h>

#define NN 100000
#define NE 3200000
#define NNZT (NE + NN)
#define DIM 256
#define WCOLS 2048

typedef __bf16 v8bf __attribute__((ext_vector_type(8)));
typedef float f32x4 __attribute__((ext_vector_type(4)));
typedef float f32x2 __attribute__((ext_vector_type(2)));

__device__ __forceinline__ unsigned f2bfu(float f){
  unsigned u = __builtin_bit_cast(unsigned, f);
  return (u + 0x7FFFu + ((u >> 16) & 1u)) >> 16;
}
__device__ __forceinline__ float lrelu(float x){ return fmaxf(x, 0.2f * x); }
__device__ __forceinline__ int imin(int a, int b){ return a < b ? a : b; }
__device__ __forceinline__ unsigned char f2fp8(float f){
  return (unsigned char)(__builtin_amdgcn_cvt_pk_fp8_f32(f, f, 0, false) & 0xff);
}
// 8 fp8 bytes (uint2) -> v8bf (8 bf16), element order preserved
__device__ __forceinline__ v8bf fp8x8_to_bf16(uint2 raw){
  f32x2 f01 = __builtin_amdgcn_cvt_pk_f32_fp8((int)raw.x, false);
  f32x2 f23 = __builtin_amdgcn_cvt_pk_f32_fp8((int)raw.x, true);
  f32x2 f45 = __builtin_amdgcn_cvt_pk_f32_fp8((int)raw.y, false);
  f32x2 f67 = __builtin_amdgcn_cvt_pk_f32_fp8((int)raw.y, true);
  v8bf r;
  r[0] = (__bf16)f01[0]; r[1] = (__bf16)f01[1];
  r[2] = (__bf16)f23[0]; r[3] = (__bf16)f23[1];
  r[4] = (__bf16)f45[0]; r[5] = (__bf16)f45[1];
  r[6] = (__bf16)f67[0]; r[7] = (__bf16)f67[1];
  return r;
}
// async global -> LDS, 16B per lane; LDS dest is wave-uniform base + lane*16
__device__ __forceinline__ void gl_lds16(const void* g, void* l){
  __builtin_amdgcn_global_load_lds(
      (const __attribute__((address_space(1))) void*)g,
      (__attribute__((address_space(3))) void*)l, 16, 0, 0);
}
__device__ __forceinline__ long long mk64(unsigned lo, unsigned hi){
  return (long long)(((unsigned long long)hi << 32) | lo);
}

// ---- cast x fp32 -> fp8 (4 elems/thread) ----
__global__ void k_cast_x8(const float* __restrict__ x, unsigned char* __restrict__ x8){
  int t = blockIdx.x * 256 + threadIdx.x;           // 6.4M threads exact
  float4 v = ((const float4*)x)[t];
  int lo = __builtin_amdgcn_cvt_pk_fp8_f32(v.x, v.y, 0, false);
  int both = __builtin_amdgcn_cvt_pk_fp8_f32(v.z, v.w, lo, true);
  ((int*)x8)[t] = both;
}

// ---- WaggT8[j][h*256+d] = fp8( W[d][h*256+j] * 8 )  ([256][2048] fp8) ----
__global__ void k_make_waggt8(const float* __restrict__ W, unsigned char* __restrict__ bt8){
  int t = blockIdx.x * 256 + threadIdx.x;           // 524288
  int d = t >> 11, c = t & 2047;                    // W flat index = d*2048 + c
  bt8[(size_t)(c & 255) * WCOLS + (c >> 8) * 256 + d] = f2fp8(W[t] * 8.0f);
}

// ---- Vt[h][k] = sum_d W[k][h*256+d]*a_s[h][d]; Vt[8+h][k] same with a_d (bf16) ----
__global__ void k_make_vt(const float* __restrict__ W, const float* __restrict__ as_,
                          const float* __restrict__ ad_, unsigned short* __restrict__ vt){
  int h = blockIdx.x, k = threadIdx.x;              // 8 x 256
  const float* wr = W + (size_t)k * WCOLS + h * 256;
  const float* a1 = as_ + h * 256;
  const float* a2 = ad_ + h * 256;
  float ss = 0.f, sd = 0.f;
  for (int d = 0; d < 256; ++d){ float wv = wr[d]; ss += wv * a1[d]; sd += wv * a2[d]; }
  vt[h * 256 + k] = (unsigned short)f2bfu(ss);
  vt[(8 + h) * 256 + k] = (unsigned short)f2bfu(sd);
}

// ---- CSR build (structure identical to the round-2/7/10/12/13 PASSING kernels) ----
__global__ void k_zero_col(int* __restrict__ col){
  int t = blockIdx.x * 256 + threadIdx.x;
  if (t < NNZT) col[t] = 0;
}
__global__ void k_deg_init(int* __restrict__ deg){
  int t = blockIdx.x * 256 + threadIdx.x;
  if (t < NN) deg[t] = 1;                            // self-loop
}
__global__ void k_hist(const int* __restrict__ ei, int* __restrict__ deg){
  int t = blockIdx.x * 256 + threadIdx.x;            // NE threads exact
  int d = ei[NE + t];
  if ((unsigned)d < NN) atomicAdd(&deg[d], 1);
}
__global__ void __launch_bounds__(1024) k_scan(const int* __restrict__ deg,
                                               int* __restrict__ rp, int* cur){
  __shared__ int ps[1024];
  int t = threadIdx.x;
  int lo = t * 98;
  int hi = lo + 98; if (hi > NN) hi = NN; if (lo > NN) lo = NN;
  int s = 0;
  for (int i = lo; i < hi; ++i) s += deg[i];
  ps[t] = s;
  __syncthreads();
  if (t == 0){
    int run = 0;
    for (int i = 0; i < 1024; ++i){ int v = ps[i]; ps[i] = run; run += v; }
    rp[NN] = run;
  }
  __syncthreads();
  int run = ps[t];
  for (int i = lo; i < hi; ++i){
    int dv = deg[i];
    rp[i] = run; cur[i] = run;
    run += dv;
  }
}
__global__ void k_fill_self(int* __restrict__ cur, int* __restrict__ col){
  int t = blockIdx.x * 256 + threadIdx.x;
  if (t < NN){
    int s = atomicAdd(&cur[t], 1);
    if ((unsigned)s < NNZT) col[s] = t;
  }
}
__global__ void k_fill_edge(const int* __restrict__ ei, int* __restrict__ cur, int* __restrict__ col){
  int t = blockIdx.x * 256 + threadIdx.x;
  int s = ei[t], d = ei[NE + t];
  if ((unsigned)d >= NN) return;                     // matches k_hist guard
  if ((unsigned)s >= NN) s = d;
  int slot = atomicAdd(&cur[d], 1);
  if ((unsigned)slot < NNZT) col[slot] = s;
}

// ---- per-layer P/Q: out = relu?(acc*P + Q); P carries the fp8-GEMM /64 fold ----
__global__ void k_pq(const float* g, const float* be, const float* m, const float* v,
                     const float* __restrict__ b, int has_bn,
                     float* __restrict__ P, float* __restrict__ Q){
  int j = threadIdx.x;
  if (has_bn){
    float A = g[j] * rsqrtf(v[j] + 1e-5f);
    P[j] = A * 0.015625f;                            // A/64
    Q[j] = (b[j] - m[j]) * A + be[j];
  } else {
    P[j] = 0.015625f;                                // 1/64
    Q[j] = b[j];
  }
}

// ---- alpha: [als|ald] = x8 @ Vt^T via one MFMA wave per 16 nodes (r11-proven) ----
__global__ void __launch_bounds__(256) k_alpha8(const unsigned char* __restrict__ x8,
    const unsigned short* __restrict__ vt,
    float* __restrict__ als, float* __restrict__ ald){
  int tile = blockIdx.x * 4 + (threadIdx.x >> 6);
  if (tile >= NN / 16) return;                       // 6250 exact
  int lane = threadIdx.x & 63;
  int ri = lane & 15, kg = lane >> 4;
  size_t m0 = (size_t)tile * 16;
  const unsigned char* arow = x8 + (m0 + ri) * DIM;  // row ri of the 16-node tile
  const int4* B = (const int4*)vt;                   // [16][256] bf16
  f32x4 acc = {0.f, 0.f, 0.f, 0.f};
  #pragma unroll
  for (int ks = 0; ks < 8; ++ks){
    uint2 raw = *(const uint2*)(arow + (ks * 4 + kg) * 8);
    v8bf av = fp8x8_to_bf16(raw);
    v8bf bv = __builtin_bit_cast(v8bf, B[ri * 32 + ks * 4 + kg]);
    acc = __builtin_amdgcn_mfma_f32_16x16x32_bf16(av, bv, acc, 0, 0, 0);
  }
  #pragma unroll
  for (int r = 0; r < 4; ++r){
    size_t m = m0 + kg * 4 + r;
    if (ri < 8) als[m * 8 + ri] = acc[r];
    else        ald[m * 8 + (ri - 8)] = acc[r];
  }
}

// ---- aggregation, remapped: lane owns dims lane*4..+3 for ALL 8 heads.
// Phase A (per 8-edge chunk): lane=(edge slot e=lane>>3, head h=lane&7)
// computes w once per (e,h), broadcast via per-wave LDS (wave-coherent,
// no barrier: divergent per-wave trip counts). Phase B: per edge, ONE
// coalesced dword x-load + 2 cvt + 32 scalar fmaf; 8-deep load pipeline.
__global__ void __launch_bounds__(256) k_aggregate_x8(const unsigned char* __restrict__ x8,
    const float* __restrict__ als, const float* __restrict__ ald,
    const int* __restrict__ rp, const int* __restrict__ col,
    unsigned char* __restrict__ z8){
  __shared__ __align__(16) float wbuf[4][8][8];      // [wave][edge][head]
  __shared__ __align__(16) int   sbuf[4][8];
  __shared__ __align__(16) float dbuf[4][8];
  int wid = threadIdx.x >> 6;
  int lane = threadIdx.x & 63;
  int n = blockIdx.x * 4 + wid;                      // 100000 exact
  int eh_e = lane >> 3, eh_h = lane & 7;
  int start = rp[n], end = rp[n + 1];
  if (start < 0) start = 0;
  if (end > NNZT) end = NNZT;
  if (end < start) end = start;
  float aldv = ald[(size_t)n * 8 + eh_h];
  const unsigned char* xlane = x8 + lane * 4;

  float acc[8][4];
  #pragma unroll
  for (int h = 0; h < 8; ++h)
    #pragma unroll
    for (int d = 0; d < 4; ++d) acc[h][d] = 0.f;

  float denp = 0.f;
  for (int c = start; c < end; c += 8){
    // phase A
    int e = c + eh_e;
    float w = 0.f; int src = n;
    if (e < end){
      src = col[e];
      if ((unsigned)src >= NN) src = n;
      w = __expf(lrelu(als[(size_t)src * 8 + eh_h] + aldv));
    }
    wbuf[wid][eh_e][eh_h] = w;
    if (eh_h == 0) sbuf[wid][eh_e] = src;
    denp += w;
    asm volatile("" ::: "memory");                   // order LDS write -> read (in-order per wave)
    int4 s03 = *(const int4*)&sbuf[wid][0];
    int4 s47 = *(const int4*)&sbuf[wid][4];
    int ss[8] = {s03.x, s03.y, s03.z, s03.w, s47.x, s47.y, s47.z, s47.w};
    // phase B: 8 edges, loads independent (8-deep MLP)
    #pragma unroll
    for (int j = 0; j < 8; ++j){
      unsigned xd = *(const unsigned*)(xlane + (size_t)ss[j] * DIM);
      f32x2 x01 = __builtin_amdgcn_cvt_pk_f32_fp8((int)xd, false);
      f32x2 x23 = __builtin_amdgcn_cvt_pk_f32_fp8((int)xd, true);
      float x0 = x01[0], x1 = x01[1], x2 = x23[0], x3 = x23[1];
      float4 wA = *(const float4*)&wbuf[wid][j][0];
      float4 wB = *(const float4*)&wbuf[wid][j][4];
      acc[0][0] = fmaf(wA.x, x0, acc[0][0]); acc[0][1] = fmaf(wA.x, x1, acc[0][1]);
      acc[0][2] = fmaf(wA.x, x2, acc[0][2]); acc[0][3] = fmaf(wA.x, x3, acc[0][3]);
      acc[1][0] = fmaf(wA.y, x0, acc[1][0]); acc[1][1] = fmaf(wA.y, x1, acc[1][1]);
      acc[1][2] = fmaf(wA.y, x2, acc[1][2]); acc[1][3] = fmaf(wA.y, x3, acc[1][3]);
      acc[2][0] = fmaf(wA.z, x0, acc[2][0]); acc[2][1] = fmaf(wA.z, x1, acc[2][1]);
      acc[2][2] = fmaf(wA.z, x2, acc[2][2]); acc[2][3] = fmaf(wA.z, x3, acc[2][3]);
      acc[3][0] = fmaf(wA.w, x0, acc[3][0]); acc[3][1] = fmaf(wA.w, x1, acc[3][1]);
      acc[3][2] = fmaf(wA.w, x2, acc[3][2]); acc[3][3] = fmaf(wA.w, x3, acc[3][3]);
      acc[4][0] = fmaf(wB.x, x0, acc[4][0]); acc[4][1] = fmaf(wB.x, x1, acc[4][1]);
      acc[4][2] = fmaf(wB.x, x2, acc[4][2]); acc[4][3] = fmaf(wB.x, x3, acc[4][3]);
      acc[5][0] = fmaf(wB.y, x0, acc[5][0]); acc[5][1] = fmaf(wB.y, x1, acc[5][1]);
      acc[5][2] = fmaf(wB.y, x2, acc[5][2]); acc[5][3] = fmaf(wB.y, x3, acc[5][3]);
      acc[6][0] = fmaf(wB.z, x0, acc[6][0]); acc[6][1] = fmaf(wB.z, x1, acc[6][1]);
      acc[6][2] = fmaf(wB.z, x2, acc[6][2]); acc[6][3] = fmaf(wB.z, x3, acc[6][3]);
      acc[7][0] = fmaf(wB.w, x0, acc[7][0]); acc[7][1] = fmaf(wB.w, x1, acc[7][1]);
      acc[7][2] = fmaf(wB.w, x2, acc[7][2]); acc[7][3] = fmaf(wB.w, x3, acc[7][3]);
    }
  }
  // den: reduce over edge-slot lanes (bits 3,4,5), invert, broadcast via LDS
  denp += __shfl_xor(denp, 8, 64);
  denp += __shfl_xor(denp, 16, 64);
  denp += __shfl_xor(denp, 32, 64);
  if (eh_e == 0) dbuf[wid][eh_h] = 1.0f / denp;      // lanes 0..7
  asm volatile("" ::: "memory");
  float4 rA = *(const float4*)&dbuf[wid][0];
  float4 rB = *(const float4*)&dbuf[wid][4];
  float rr[8] = {rA.x, rA.y, rA.z, rA.w, rB.x, rB.y, rB.z, rB.w};
  unsigned char* zrow = z8 + (size_t)n * WCOLS + lane * 4;
  #pragma unroll
  for (int h = 0; h < 8; ++h){
    float v0 = acc[h][0] * rr[h], v1 = acc[h][1] * rr[h];
    float v2 = acc[h][2] * rr[h], v3 = acc[h][3] * rr[h];
    int lo = __builtin_amdgcn_cvt_pk_fp8_f32(v0, v1, 0, false);
    int pk = __builtin_amdgcn_cvt_pk_fp8_f32(v2, v3, lo, true);
    *(unsigned*)(zrow + h * 256) = (unsigned)pk;     // coalesced per head
  }
}

// ---- big GEMM, full fp8 + double-buffered global_load_lds pipeline ----
// r13-proven addressing; buf^1 staged right after the single barrier so the
// 3 gl_lds fly under the 32 MFMAs (T3 minimum-2-phase, zero VGPR cost).
__global__ void __launch_bounds__(512) k_gemm2(const unsigned char* __restrict__ z8,
    const unsigned char* __restrict__ bt8,
    const float* __restrict__ Pb, const float* __restrict__ Qb,
    unsigned char* __restrict__ x8out, float* __restrict__ fout, int last){
  __shared__ __align__(16) unsigned char sA[2][128 * 64];   // 2 x 8 KB
  __shared__ __align__(16) unsigned char sB[2][256 * 64];   // 2 x 16 KB
  int tid = threadIdx.x;
  int w = tid >> 6, lane = tid & 63;
  int wr = w >> 2, wc = w & 3;
  int ri = lane & 15, kg = lane >> 4;
  int m0 = blockIdx.x * 128;

  // staging source addresses (16B units, swizzled on the global side)
  int rowU = tid >> 2;                         // 0..127
  int gblk = (tid & 3) ^ ((tid >> 3) & 3);     // = (u&3) ^ ((row>>1)&3)
  int rA = imin(m0 + rowU, NN - 1);
  const unsigned char* gA  = z8  + (size_t)rA * WCOLS + gblk * 16;
  const unsigned char* gB0 = bt8 + (size_t)rowU * WCOLS + gblk * 16;          // rows 0..127
  const unsigned char* gB1 = bt8 + (size_t)(128 + rowU) * WCOLS + gblk * 16;  // rows 128..255
  int woff = w << 10;

  f32x4 acc[4][4];
  #pragma unroll
  for (int i = 0; i < 4; ++i)
    #pragma unroll
    for (int j = 0; j < 4; ++j) acc[i][j] = (f32x4){0.f, 0.f, 0.f, 0.f};

  // prologue: stage t=0 into buffer 0
  gl_lds16(gA,  &sA[0][woff]);
  gl_lds16(gB0, &sB[0][woff]);
  gl_lds16(gB1, &sB[0][8192 + woff]);

  int cur = 0;
  for (int t = 0; t < 32; ++t){
    __syncthreads();                           // drains own vmcnt+lgkmcnt -> buf[cur] ready, buf[cur^1] free
    if (t < 31){
      int kn = (t + 1) * 64;
      gl_lds16(gA + kn,  &sA[cur ^ 1][woff]);
      gl_lds16(gB0 + kn, &sB[cur ^ 1][woff]);
      gl_lds16(gB1 + kn, &sB[cur ^ 1][8192 + woff]);
    }
    const unsigned char* a_base = &sA[cur][0];
    const unsigned char* b_base = &sB[cur][0];
    long long aLo[4], aHi[4], bLo[4], bHi[4];
    #pragma unroll
    for (int ai = 0; ai < 4; ++ai){
      int r = wr * 64 + ai * 16 + ri;
      int c = kg ^ ((r >> 1) & 3);
      uint4 av = *(const uint4*)(a_base + r * 64 + c * 16);
      aLo[ai] = mk64(av.x, av.y);
      aHi[ai] = mk64(av.z, av.w);
    }
    #pragma unroll
    for (int bj = 0; bj < 4; ++bj){
      int r = wc * 64 + bj * 16 + ri;
      int c = kg ^ ((r >> 1) & 3);
      uint4 bv = *(const uint4*)(b_base + r * 64 + c * 16);
      bLo[bj] = mk64(bv.x, bv.y);
      bHi[bj] = mk64(bv.z, bv.w);
    }
    #pragma unroll
    for (int ai = 0; ai < 4; ++ai)
      #pragma unroll
      for (int bj = 0; bj < 4; ++bj){
        acc[ai][bj] = __builtin_amdgcn_mfma_f32_16x16x32_fp8_fp8(aLo[ai], bLo[bj], acc[ai][bj], 0, 0, 0);
        acc[ai][bj] = __builtin_amdgcn_mfma_f32_16x16x32_fp8_fp8(aHi[ai], bHi[bj], acc[ai][bj], 0, 0, 0);
      }
    cur ^= 1;
  }

  // epilogue: C[m0 + wr*64 + ai*16 + kg*4 + r][wc*64 + bj*16 + ri]
  #pragma unroll
  for (int bj = 0; bj < 4; ++bj){
    int colj = wc * 64 + bj * 16 + ri;
    float p = Pb[colj], q = Qb[colj];
    #pragma unroll
    for (int ai = 0; ai < 4; ++ai){
      #pragma unroll
      for (int r = 0; r < 4; ++r){
        int row = m0 + wr * 64 + ai * 16 + kg * 4 + r;
        if (row < NN){
          float v = acc[ai][bj][r] * p + q;
          if (!last){
            v = fmaxf(v, 0.f);
            x8out[(size_t)row * DIM + colj] = f2fp8(v);
          } else {
            fout[(size_t)row * DIM + colj] = v;
          }
        }
      }
    }
  }
}

// ---- doc GEMM: [64,3072]@[3072,256] fp32, one block per row ----
__global__ void __launch_bounds__(256) k_doc(const float* __restrict__ dd,
    const float* __restrict__ dw, const float* __restrict__ db, float* __restrict__ out){
  int r = blockIdx.x;                 // 64 rows
  int j = threadIdx.x;                // 256 cols
  const float* drow = dd + (size_t)r * 3072;
  float acc = db[j];
  #pragma unroll 4
  for (int k = 0; k < 3072; ++k)
    acc = fmaf(drow[k], dw[(size_t)k * 256 + j], acc);
  out[(size_t)NN * DIM + (size_t)r * 256 + j] = acc;
}

extern "C" void kernel_launch(void* const* d_in, const int* in_sizes, int n_in,
                              void* d_out, int out_size, void* d_ws, size_t ws_size,
                              hipStream_t stream) {
  (void)in_sizes; (void)n_in; (void)out_size; (void)ws_size;
  const float* x      = (const float*)d_in[0];
  const int*   ei     = (const int*)d_in[1];
  const float* doc    = (const float*)d_in[2];
  const float* W[3]   = {(const float*)d_in[3], (const float*)d_in[7], (const float*)d_in[11]};
  const float* as_[3] = {(const float*)d_in[4], (const float*)d_in[8], (const float*)d_in[12]};
  const float* ad_[3] = {(const float*)d_in[5], (const float*)d_in[9], (const float*)d_in[13]};
  const float* b_[3]  = {(const float*)d_in[6], (const float*)d_in[10], (const float*)d_in[14]};
  const float* bng[2] = {(const float*)d_in[15], (const float*)d_in[19]};
  const float* bnb[2] = {(const float*)d_in[16], (const float*)d_in[20]};
  const float* bnm[2] = {(const float*)d_in[17], (const float*)d_in[21]};
  const float* bnv[2] = {(const float*)d_in[18], (const float*)d_in[22]};
  const float* docW   = (const float*)d_in[23];
  const float* docB   = (const float*)d_in[24];
  float* out = (float*)d_out;

  char* ws = (char*)d_ws;
  // Same offsets as the r10/r12/r13 PASSING layout.
  unsigned char*  x8   = (unsigned char*)(ws + 0);             //  25,600,000
  unsigned char*  z8   = (unsigned char*)(ws + 25600000);      // 204,800,000
  float* als           = (float*)(ws + 230400000);             //   3,200,000
  float* ald           = (float*)(ws + 233600000);             //   3,200,000
  unsigned char* bt8   = (unsigned char*)(ws + 236800000);     //   1,572,864 used (3 x 512 KiB)
  int* rp              = (int*)(ws + 239945728);               //     400,064
  int* deg             = (int*)(ws + 240345792);               //     400,000
  int* cur             = (int*)(ws + 240745792);               //     400,000
  int* colb            = (int*)(ws + 241145792);               //  13,200,000
  unsigned short* vt   = (unsigned short*)(ws + 254345792);    //      24,576 (3 x 8 KiB)
  float* Pb            = (float*)(ws + 254394944);             //       1,024
  float* Qb            = (float*)(ws + 254395968);             //       1,024 -> end 254,396,992

  // input prep
  k_cast_x8<<<25000, 256, 0, stream>>>(x, x8);
  for (int L = 0; L < 3; ++L){
    k_make_waggt8<<<2048, 256, 0, stream>>>(W[L], bt8 + (size_t)L * 524288);
    k_make_vt<<<8, 256, 0, stream>>>(W[L], as_[L], ad_[L], vt + (size_t)L * 4096);
  }

  // CSR (shared by all 3 layers); deg/cur strictly distinct buffers
  k_zero_col<<<12891, 256, 0, stream>>>(colb);
  k_deg_init<<<391, 256, 0, stream>>>(deg);
  k_hist<<<12500, 256, 0, stream>>>(ei, deg);
  k_scan<<<1, 1024, 0, stream>>>(deg, rp, cur);
  k_fill_self<<<391, 256, 0, stream>>>(cur, colb);
  k_fill_edge<<<12500, 256, 0, stream>>>(ei, cur, colb);

  // layers
  for (int L = 0; L < 3; ++L){
    int has_bn = (L < 2) ? 1 : 0;
    k_pq<<<1, 256, 0, stream>>>(has_bn ? bng[L] : nullptr, has_bn ? bnb[L] : nullptr,
                                has_bn ? bnm[L] : nullptr, has_bn ? bnv[L] : nullptr,
                                b_[L], has_bn, Pb, Qb);
    k_alpha8<<<1563, 256, 0, stream>>>(x8, vt + (size_t)L * 4096, als, ald);
    k_aggregate_x8<<<25000, 256, 0, stream>>>(x8, als, ald, rp, colb, z8);
    k_gemm2<<<782, 512, 0, stream>>>(z8, bt8 + (size_t)L * 524288, Pb, Qb,
                                     x8, out, (L == 2) ? 1 : 0);
  }

  // doc branch
  k_doc<<<64, 256, 0, stream>>>(doc, docW, docB, out);
}

// Round 15
// 1920.552 us; speedup vs baseline: 1.8280x; 1.1458x over previous
//
#include <hip/hip_runtime.h>
#include <stdint.h>

#define NN 100000
#define NE 3200000
#define NNZT (NE + NN)
#define DIM 256
#define WCOLS 2048

typedef __bf16 v8bf __attribute__((ext_vector_type(8)));
typedef float f32x4 __attribute__((ext_vector_type(4)));
typedef float f32x2 __attribute__((ext_vector_type(2)));

__device__ __forceinline__ unsigned f2bfu(float f){
  unsigned u = __builtin_bit_cast(unsigned, f);
  return (u + 0x7FFFu + ((u >> 16) & 1u)) >> 16;
}
__device__ __forceinline__ float lrelu(float x){ return fmaxf(x, 0.2f * x); }
__device__ __forceinline__ int imin(int a, int b){ return a < b ? a : b; }
__device__ __forceinline__ unsigned char f2fp8(float f){
  return (unsigned char)(__builtin_amdgcn_cvt_pk_fp8_f32(f, f, 0, false) & 0xff);
}
// 8 fp8 bytes (uint2) -> v8bf (8 bf16), element order preserved
__device__ __forceinline__ v8bf fp8x8_to_bf16(uint2 raw){
  f32x2 f01 = __builtin_amdgcn_cvt_pk_f32_fp8((int)raw.x, false);
  f32x2 f23 = __builtin_amdgcn_cvt_pk_f32_fp8((int)raw.x, true);
  f32x2 f45 = __builtin_amdgcn_cvt_pk_f32_fp8((int)raw.y, false);
  f32x2 f67 = __builtin_amdgcn_cvt_pk_f32_fp8((int)raw.y, true);
  v8bf r;
  r[0] = (__bf16)f01[0]; r[1] = (__bf16)f01[1];
  r[2] = (__bf16)f23[0]; r[3] = (__bf16)f23[1];
  r[4] = (__bf16)f45[0]; r[5] = (__bf16)f45[1];
  r[6] = (__bf16)f67[0]; r[7] = (__bf16)f67[1];
  return r;
}
// async global -> LDS, 16B per lane; LDS dest is wave-uniform base + lane*16
__device__ __forceinline__ void gl_lds16(const void* g, void* l){
  __builtin_amdgcn_global_load_lds(
      (const __attribute__((address_space(1))) void*)g,
      (__attribute__((address_space(3))) void*)l, 16, 0, 0);
}
__device__ __forceinline__ long long mk64(unsigned lo, unsigned hi){
  return (long long)(((unsigned long long)hi << 32) | lo);
}

// ---- cast x fp32 -> fp8 (4 elems/thread) ----
__global__ void k_cast_x8(const float* __restrict__ x, unsigned char* __restrict__ x8){
  int t = blockIdx.x * 256 + threadIdx.x;           // 6.4M threads exact
  float4 v = ((const float4*)x)[t];
  int lo = __builtin_amdgcn_cvt_pk_fp8_f32(v.x, v.y, 0, false);
  int both = __builtin_amdgcn_cvt_pk_fp8_f32(v.z, v.w, lo, true);
  ((int*)x8)[t] = both;
}

// ---- WaggT8[j][h*256+d] = fp8( W[d][h*256+j] * 8 )  ([256][2048] fp8) ----
__global__ void k_make_waggt8(const float* __restrict__ W, unsigned char* __restrict__ bt8){
  int t = blockIdx.x * 256 + threadIdx.x;           // 524288
  int d = t >> 11, c = t & 2047;                    // W flat index = d*2048 + c
  bt8[(size_t)(c & 255) * WCOLS + (c >> 8) * 256 + d] = f2fp8(W[t] * 8.0f);
}

// ---- Vt[h][k] = sum_d W[k][h*256+d]*a_s[h][d]; Vt[8+h][k] same with a_d (bf16) ----
__global__ void k_make_vt(const float* __restrict__ W, const float* __restrict__ as_,
                          const float* __restrict__ ad_, unsigned short* __restrict__ vt){
  int h = blockIdx.x, k = threadIdx.x;              // 8 x 256
  const float* wr = W + (size_t)k * WCOLS + h * 256;
  const float* a1 = as_ + h * 256;
  const float* a2 = ad_ + h * 256;
  float ss = 0.f, sd = 0.f;
  for (int d = 0; d < 256; ++d){ float wv = wr[d]; ss += wv * a1[d]; sd += wv * a2[d]; }
  vt[h * 256 + k] = (unsigned short)f2bfu(ss);
  vt[(8 + h) * 256 + k] = (unsigned short)f2bfu(sd);
}

// ---- CSR build (structure identical to the round-2/7/10/12/13/14 PASSING kernels) ----
__global__ void k_zero_col(int* __restrict__ col){
  int t = blockIdx.x * 256 + threadIdx.x;
  if (t < NNZT) col[t] = 0;
}
__global__ void k_deg_init(int* __restrict__ deg){
  int t = blockIdx.x * 256 + threadIdx.x;
  if (t < NN) deg[t] = 1;                            // self-loop
}
__global__ void k_hist(const int* __restrict__ ei, int* __restrict__ deg){
  int t = blockIdx.x * 256 + threadIdx.x;            // NE threads exact
  int d = ei[NE + t];
  if ((unsigned)d < NN) atomicAdd(&deg[d], 1);
}
__global__ void __launch_bounds__(1024) k_scan(const int* __restrict__ deg,
                                               int* __restrict__ rp, int* cur){
  __shared__ int ps[1024];
  int t = threadIdx.x;
  int lo = t * 98;
  int hi = lo + 98; if (hi > NN) hi = NN; if (lo > NN) lo = NN;
  int s = 0;
  for (int i = lo; i < hi; ++i) s += deg[i];
  ps[t] = s;
  __syncthreads();
  if (t == 0){
    int run = 0;
    for (int i = 0; i < 1024; ++i){ int v = ps[i]; ps[i] = run; run += v; }
    rp[NN] = run;
  }
  __syncthreads();
  int run = ps[t];
  for (int i = lo; i < hi; ++i){
    int dv = deg[i];
    rp[i] = run; cur[i] = run;
    run += dv;
  }
}
__global__ void k_fill_self(int* __restrict__ cur, int* __restrict__ col){
  int t = blockIdx.x * 256 + threadIdx.x;
  if (t < NN){
    int s = atomicAdd(&cur[t], 1);
    if ((unsigned)s < NNZT) col[s] = t;
  }
}
__global__ void k_fill_edge(const int* __restrict__ ei, int* __restrict__ cur, int* __restrict__ col){
  int t = blockIdx.x * 256 + threadIdx.x;
  int s = ei[t], d = ei[NE + t];
  if ((unsigned)d >= NN) return;                     // matches k_hist guard
  if ((unsigned)s >= NN) s = d;
  int slot = atomicAdd(&cur[d], 1);
  if ((unsigned)slot < NNZT) col[slot] = s;
}

// ---- per-layer P/Q: out = relu?(acc*P + Q); P carries the fp8-GEMM /64 fold ----
__global__ void k_pq(const float* g, const float* be, const float* m, const float* v,
                     const float* __restrict__ b, int has_bn,
                     float* __restrict__ P, float* __restrict__ Q){
  int j = threadIdx.x;
  if (has_bn){
    float A = g[j] * rsqrtf(v[j] + 1e-5f);
    P[j] = A * 0.015625f;                            // A/64
    Q[j] = (b[j] - m[j]) * A + be[j];
  } else {
    P[j] = 0.015625f;                                // 1/64
    Q[j] = b[j];
  }
}

// ---- alpha: [als|ald] = x8 @ Vt^T via one MFMA wave per 16 nodes (r11-proven) ----
__global__ void __launch_bounds__(256) k_alpha8(const unsigned char* __restrict__ x8,
    const unsigned short* __restrict__ vt,
    float* __restrict__ als, float* __restrict__ ald){
  int tile = blockIdx.x * 4 + (threadIdx.x >> 6);
  if (tile >= NN / 16) return;                       // 6250 exact
  int lane = threadIdx.x & 63;
  int ri = lane & 15, kg = lane >> 4;
  size_t m0 = (size_t)tile * 16;
  const unsigned char* arow = x8 + (m0 + ri) * DIM;  // row ri of the 16-node tile
  const int4* B = (const int4*)vt;                   // [16][256] bf16
  f32x4 acc = {0.f, 0.f, 0.f, 0.f};
  #pragma unroll
  for (int ks = 0; ks < 8; ++ks){
    uint2 raw = *(const uint2*)(arow + (ks * 4 + kg) * 8);
    v8bf av = fp8x8_to_bf16(raw);
    v8bf bv = __builtin_bit_cast(v8bf, B[ri * 32 + ks * 4 + kg]);
    acc = __builtin_amdgcn_mfma_f32_16x16x32_bf16(av, bv, acc, 0, 0, 0);
  }
  #pragma unroll
  for (int r = 0; r < 4; ++r){
    size_t m = m0 + kg * 4 + r;
    if (ri < 8) als[m * 8 + ri] = acc[r];
    else        ald[m * 8 + (ri - 8)] = acc[r];
  }
}

// ---- aggregation (EXACT r14-proven remapped version) ----
__global__ void __launch_bounds__(256) k_aggregate_x8(const unsigned char* __restrict__ x8,
    const float* __restrict__ als, const float* __restrict__ ald,
    const int* __restrict__ rp, const int* __restrict__ col,
    unsigned char* __restrict__ z8){
  __shared__ __align__(16) float wbuf[4][8][8];      // [wave][edge][head]
  __shared__ __align__(16) int   sbuf[4][8];
  __shared__ __align__(16) float dbuf[4][8];
  int wid = threadIdx.x >> 6;
  int lane = threadIdx.x & 63;
  int n = blockIdx.x * 4 + wid;                      // 100000 exact
  int eh_e = lane >> 3, eh_h = lane & 7;
  int start = rp[n], end = rp[n + 1];
  if (start < 0) start = 0;
  if (end > NNZT) end = NNZT;
  if (end < start) end = start;
  float aldv = ald[(size_t)n * 8 + eh_h];
  const unsigned char* xlane = x8 + lane * 4;

  float acc[8][4];
  #pragma unroll
  for (int h = 0; h < 8; ++h)
    #pragma unroll
    for (int d = 0; d < 4; ++d) acc[h][d] = 0.f;

  float denp = 0.f;
  for (int c = start; c < end; c += 8){
    // phase A
    int e = c + eh_e;
    float w = 0.f; int src = n;
    if (e < end){
      src = col[e];
      if ((unsigned)src >= NN) src = n;
      w = __expf(lrelu(als[(size_t)src * 8 + eh_h] + aldv));
    }
    wbuf[wid][eh_e][eh_h] = w;
    if (eh_h == 0) sbuf[wid][eh_e] = src;
    denp += w;
    asm volatile("" ::: "memory");                   // order LDS write -> read (in-order per wave)
    int4 s03 = *(const int4*)&sbuf[wid][0];
    int4 s47 = *(const int4*)&sbuf[wid][4];
    int ss[8] = {s03.x, s03.y, s03.z, s03.w, s47.x, s47.y, s47.z, s47.w};
    // phase B: 8 edges, loads independent (8-deep MLP)
    #pragma unroll
    for (int j = 0; j < 8; ++j){
      unsigned xd = *(const unsigned*)(xlane + (size_t)ss[j] * DIM);
      f32x2 x01 = __builtin_amdgcn_cvt_pk_f32_fp8((int)xd, false);
      f32x2 x23 = __builtin_amdgcn_cvt_pk_f32_fp8((int)xd, true);
      float x0 = x01[0], x1 = x01[1], x2 = x23[0], x3 = x23[1];
      float4 wA = *(const float4*)&wbuf[wid][j][0];
      float4 wB = *(const float4*)&wbuf[wid][j][4];
      acc[0][0] = fmaf(wA.x, x0, acc[0][0]); acc[0][1] = fmaf(wA.x, x1, acc[0][1]);
      acc[0][2] = fmaf(wA.x, x2, acc[0][2]); acc[0][3] = fmaf(wA.x, x3, acc[0][3]);
      acc[1][0] = fmaf(wA.y, x0, acc[1][0]); acc[1][1] = fmaf(wA.y, x1, acc[1][1]);
      acc[1][2] = fmaf(wA.y, x2, acc[1][2]); acc[1][3] = fmaf(wA.y, x3, acc[1][3]);
      acc[2][0] = fmaf(wA.z, x0, acc[2][0]); acc[2][1] = fmaf(wA.z, x1, acc[2][1]);
      acc[2][2] = fmaf(wA.z, x2, acc[2][2]); acc[2][3] = fmaf(wA.z, x3, acc[2][3]);
      acc[3][0] = fmaf(wA.w, x0, acc[3][0]); acc[3][1] = fmaf(wA.w, x1, acc[3][1]);
      acc[3][2] = fmaf(wA.w, x2, acc[3][2]); acc[3][3] = fmaf(wA.w, x3, acc[3][3]);
      acc[4][0] = fmaf(wB.x, x0, acc[4][0]); acc[4][1] = fmaf(wB.x, x1, acc[4][1]);
      acc[4][2] = fmaf(wB.x, x2, acc[4][2]); acc[4][3] = fmaf(wB.x, x3, acc[4][3]);
      acc[5][0] = fmaf(wB.y, x0, acc[5][0]); acc[5][1] = fmaf(wB.y, x1, acc[5][1]);
      acc[5][2] = fmaf(wB.y, x2, acc[5][2]); acc[5][3] = fmaf(wB.y, x3, acc[5][3]);
      acc[6][0] = fmaf(wB.z, x0, acc[6][0]); acc[6][1] = fmaf(wB.z, x1, acc[6][1]);
      acc[6][2] = fmaf(wB.z, x2, acc[6][2]); acc[6][3] = fmaf(wB.z, x3, acc[6][3]);
      acc[7][0] = fmaf(wB.w, x0, acc[7][0]); acc[7][1] = fmaf(wB.w, x1, acc[7][1]);
      acc[7][2] = fmaf(wB.w, x2, acc[7][2]); acc[7][3] = fmaf(wB.w, x3, acc[7][3]);
    }
  }
  // den: reduce over edge-slot lanes (bits 3,4,5), invert, broadcast via LDS
  denp += __shfl_xor(denp, 8, 64);
  denp += __shfl_xor(denp, 16, 64);
  denp += __shfl_xor(denp, 32, 64);
  if (eh_e == 0) dbuf[wid][eh_h] = 1.0f / denp;      // lanes 0..7
  asm volatile("" ::: "memory");
  float4 rA = *(const float4*)&dbuf[wid][0];
  float4 rB = *(const float4*)&dbuf[wid][4];
  float rr[8] = {rA.x, rA.y, rA.z, rA.w, rB.x, rB.y, rB.z, rB.w};
  unsigned char* zrow = z8 + (size_t)n * WCOLS + lane * 4;
  #pragma unroll
  for (int h = 0; h < 8; ++h){
    float v0 = acc[h][0] * rr[h], v1 = acc[h][1] * rr[h];
    float v2 = acc[h][2] * rr[h], v3 = acc[h][3] * rr[h];
    int lo = __builtin_amdgcn_cvt_pk_fp8_f32(v0, v1, 0, false);
    int pk = __builtin_amdgcn_cvt_pk_fp8_f32(v2, v3, lo, true);
    *(unsigned*)(zrow + h * 256) = (unsigned)pk;     // coalesced per head
  }
}

// ---- big GEMM (EXACT r14-proven fp8 + double-buffered gl_lds pipeline) ----
__global__ void __launch_bounds__(512) k_gemm2(const unsigned char* __restrict__ z8,
    const unsigned char* __restrict__ bt8,
    const float* __restrict__ Pb, const float* __restrict__ Qb,
    unsigned char* __restrict__ x8out, float* __restrict__ fout, int last){
  __shared__ __align__(16) unsigned char sA[2][128 * 64];   // 2 x 8 KB
  __shared__ __align__(16) unsigned char sB[2][256 * 64];   // 2 x 16 KB
  int tid = threadIdx.x;
  int w = tid >> 6, lane = tid & 63;
  int wr = w >> 2, wc = w & 3;
  int ri = lane & 15, kg = lane >> 4;
  int m0 = blockIdx.x * 128;

  // staging source addresses (16B units, swizzled on the global side)
  int rowU = tid >> 2;                         // 0..127
  int gblk = (tid & 3) ^ ((tid >> 3) & 3);     // = (u&3) ^ ((row>>1)&3)
  int rA = imin(m0 + rowU, NN - 1);
  const unsigned char* gA  = z8  + (size_t)rA * WCOLS + gblk * 16;
  const unsigned char* gB0 = bt8 + (size_t)rowU * WCOLS + gblk * 16;          // rows 0..127
  const unsigned char* gB1 = bt8 + (size_t)(128 + rowU) * WCOLS + gblk * 16;  // rows 128..255
  int woff = w << 10;

  f32x4 acc[4][4];
  #pragma unroll
  for (int i = 0; i < 4; ++i)
    #pragma unroll
    for (int j = 0; j < 4; ++j) acc[i][j] = (f32x4){0.f, 0.f, 0.f, 0.f};

  // prologue: stage t=0 into buffer 0
  gl_lds16(gA,  &sA[0][woff]);
  gl_lds16(gB0, &sB[0][woff]);
  gl_lds16(gB1, &sB[0][8192 + woff]);

  int cur = 0;
  for (int t = 0; t < 32; ++t){
    __syncthreads();                           // buf[cur] ready, buf[cur^1] free
    if (t < 31){
      int kn = (t + 1) * 64;
      gl_lds16(gA + kn,  &sA[cur ^ 1][woff]);
      gl_lds16(gB0 + kn, &sB[cur ^ 1][woff]);
      gl_lds16(gB1 + kn, &sB[cur ^ 1][8192 + woff]);
    }
    const unsigned char* a_base = &sA[cur][0];
    const unsigned char* b_base = &sB[cur][0];
    long long aLo[4], aHi[4], bLo[4], bHi[4];
    #pragma unroll
    for (int ai = 0; ai < 4; ++ai){
      int r = wr * 64 + ai * 16 + ri;
      int c = kg ^ ((r >> 1) & 3);
      uint4 av = *(const uint4*)(a_base + r * 64 + c * 16);
      aLo[ai] = mk64(av.x, av.y);
      aHi[ai] = mk64(av.z, av.w);
    }
    #pragma unroll
    for (int bj = 0; bj < 4; ++bj){
      int r = wc * 64 + bj * 16 + ri;
      int c = kg ^ ((r >> 1) & 3);
      uint4 bv = *(const uint4*)(b_base + r * 64 + c * 16);
      bLo[bj] = mk64(bv.x, bv.y);
      bHi[bj] = mk64(bv.z, bv.w);
    }
    #pragma unroll
    for (int ai = 0; ai < 4; ++ai)
      #pragma unroll
      for (int bj = 0; bj < 4; ++bj){
        acc[ai][bj] = __builtin_amdgcn_mfma_f32_16x16x32_fp8_fp8(aLo[ai], bLo[bj], acc[ai][bj], 0, 0, 0);
        acc[ai][bj] = __builtin_amdgcn_mfma_f32_16x16x32_fp8_fp8(aHi[ai], bHi[bj], acc[ai][bj], 0, 0, 0);
      }
    cur ^= 1;
  }

  // epilogue: C[m0 + wr*64 + ai*16 + kg*4 + r][wc*64 + bj*16 + ri]
  #pragma unroll
  for (int bj = 0; bj < 4; ++bj){
    int colj = wc * 64 + bj * 16 + ri;
    float p = Pb[colj], q = Qb[colj];
    #pragma unroll
    for (int ai = 0; ai < 4; ++ai){
      #pragma unroll
      for (int r = 0; r < 4; ++r){
        int row = m0 + wr * 64 + ai * 16 + kg * 4 + r;
        if (row < NN){
          float v = acc[ai][bj][r] * p + q;
          if (!last){
            v = fmaxf(v, 0.f);
            x8out[(size_t)row * DIM + colj] = f2fp8(v);
          } else {
            fout[(size_t)row * DIM + colj] = v;
          }
        }
      }
    }
  }
}

// ---- doc GEMM split-K: part[r][q][j] = sum_{k in quarter q} dd[r,k]*dw[k,j] ----
// 256 blocks (r = bid>>2, q = bid&3) x 256 threads; 768 k's each, unroll 8.
__global__ void __launch_bounds__(256) k_doc_part(const float* __restrict__ dd,
    const float* __restrict__ dw, float* __restrict__ part){
  int bid = blockIdx.x;
  int r = bid >> 2, q = bid & 3;
  int j = threadIdx.x;
  const float* drow = dd + (size_t)r * 3072 + q * 768;
  const float* wcol = dw + (size_t)q * 768 * 256 + j;
  float acc = 0.f;
  #pragma unroll 8
  for (int k = 0; k < 768; ++k)
    acc = fmaf(drow[k], wcol[(size_t)k * 256], acc);
  part[(size_t)bid * 256 + j] = acc;
}
// reduce 4 partials + bias -> out
__global__ void __launch_bounds__(256) k_doc_red(const float* __restrict__ part,
    const float* __restrict__ db, float* __restrict__ out){
  int r = blockIdx.x, j = threadIdx.x;
  size_t base = (size_t)r * 4 * 256 + j;
  float v = part[base] + part[base + 256] + part[base + 512] + part[base + 768] + db[j];
  out[(size_t)NN * DIM + (size_t)r * 256 + j] = v;
}

extern "C" void kernel_launch(void* const* d_in, const int* in_sizes, int n_in,
                              void* d_out, int out_size, void* d_ws, size_t ws_size,
                              hipStream_t stream) {
  (void)in_sizes; (void)n_in; (void)out_size; (void)ws_size;
  const float* x      = (const float*)d_in[0];
  const int*   ei     = (const int*)d_in[1];
  const float* doc    = (const float*)d_in[2];
  const float* W[3]   = {(const float*)d_in[3], (const float*)d_in[7], (const float*)d_in[11]};
  const float* as_[3] = {(const float*)d_in[4], (const float*)d_in[8], (const float*)d_in[12]};
  const float* ad_[3] = {(const float*)d_in[5], (const float*)d_in[9], (const float*)d_in[13]};
  const float* b_[3]  = {(const float*)d_in[6], (const float*)d_in[10], (const float*)d_in[14]};
  const float* bng[2] = {(const float*)d_in[15], (const float*)d_in[19]};
  const float* bnb[2] = {(const float*)d_in[16], (const float*)d_in[20]};
  const float* bnm[2] = {(const float*)d_in[17], (const float*)d_in[21]};
  const float* bnv[2] = {(const float*)d_in[18], (const float*)d_in[22]};
  const float* docW   = (const float*)d_in[23];
  const float* docB   = (const float*)d_in[24];
  float* out = (float*)d_out;

  char* ws = (char*)d_ws;
  // Same offsets as the r10/r12/r13/r14 PASSING layout; doc partials in the
  // free region past Qb (ends 254,659,200 < 279,947,840 proven bound).
  unsigned char*  x8   = (unsigned char*)(ws + 0);             //  25,600,000
  unsigned char*  z8   = (unsigned char*)(ws + 25600000);      // 204,800,000
  float* als           = (float*)(ws + 230400000);             //   3,200,000
  float* ald           = (float*)(ws + 233600000);             //   3,200,000
  unsigned char* bt8   = (unsigned char*)(ws + 236800000);     //   1,572,864 used (3 x 512 KiB)
  int* rp              = (int*)(ws + 239945728);               //     400,064
  int* deg             = (int*)(ws + 240345792);               //     400,000
  int* cur             = (int*)(ws + 240745792);               //     400,000
  int* colb            = (int*)(ws + 241145792);               //  13,200,000
  unsigned short* vt   = (unsigned short*)(ws + 254345792);    //      24,576 (3 x 8 KiB)
  float* Pb            = (float*)(ws + 254394944);             //       1,024
  float* Qb            = (float*)(ws + 254395968);             //       1,024
  float* docpart       = (float*)(ws + 254397056);             //     262,144 -> end 254,659,200

  // input prep
  k_cast_x8<<<25000, 256, 0, stream>>>(x, x8);
  for (int L = 0; L < 3; ++L){
    k_make_waggt8<<<2048, 256, 0, stream>>>(W[L], bt8 + (size_t)L * 524288);
    k_make_vt<<<8, 256, 0, stream>>>(W[L], as_[L], ad_[L], vt + (size_t)L * 4096);
  }

  // CSR (shared by all 3 layers); deg/cur strictly distinct buffers
  k_zero_col<<<12891, 256, 0, stream>>>(colb);
  k_deg_init<<<391, 256, 0, stream>>>(deg);
  k_hist<<<12500, 256, 0, stream>>>(ei, deg);
  k_scan<<<1, 1024, 0, stream>>>(deg, rp, cur);
  k_fill_self<<<391, 256, 0, stream>>>(cur, colb);
  k_fill_edge<<<12500, 256, 0, stream>>>(ei, cur, colb);

  // doc branch (split-K, deterministic)
  k_doc_part<<<256, 256, 0, stream>>>(doc, docW, docpart);
  k_doc_red<<<64, 256, 0, stream>>>(docpart, docB, out);

  // layers
  for (int L = 0; L < 3; ++L){
    int has_bn = (L < 2) ? 1 : 0;
    k_pq<<<1, 256, 0, stream>>>(has_bn ? bng[L] : nullptr, has_bn ? bnb[L] : nullptr,
                                has_bn ? bnm[L] : nullptr, has_bn ? bnv[L] : nullptr,
                                b_[L], has_bn, Pb, Qb);
    k_alpha8<<<1563, 256, 0, stream>>>(x8, vt + (size_t)L * 4096, als, ald);
    k_aggregate_x8<<<25000, 256, 0, stream>>>(x8, als, ald, rp, colb, z8);
    k_gemm2<<<782, 512, 0, stream>>>(z8, bt8 + (size_t)L * 524288, Pb, Qb,
                                     x8, out, (L == 2) ? 1 : 0);
  }
}